// Round 2
// baseline (1974.356 us; speedup 1.0000x reference)
//
#include <hip/hip_runtime.h>
#include <hip/hip_fp16.h>
#include <math.h>

#define B_SZ   2
#define S_LEN  2048
#define D_MODEL 1024
#define NH     16
#define HD     64
#define THD_   1024
#define SCALE  0.125f   // 1/sqrt(64)

// ws layout (bytes):
//   q_h : __half [b][comp][h][s][hd]  8,388,608 elems @ 0          (16.78 MB)
//   k_h : __half same                 8,388,608 elems @ 16,777,216 (16.78 MB)
//   v_h : __half [b][h][s][hd]        4,194,304 elems @ 33,554,432 ( 8.39 MB)
//   gn_out : float 4,194,304 elems @ 0  (reuses dead q region after attention)
// total ws use: 41,943,040 bytes.

__device__ inline void half8_to_float8(const __half* p, float* f) {
  float4 raw = *(const float4*)p;  // 8 halves, 16B
  const __half2* h2 = (const __half2*)&raw;
#pragma unroll
  for (int i = 0; i < 4; ++i) {
    float2 t = __half22float2(h2[i]);
    f[2 * i] = t.x;
    f[2 * i + 1] = t.y;
  }
}

// ---------------------------------------------------------------------------
// GEMM: C = A(4096 x 1024) * B(1024 x N), fp32 A/B, 128x128 tile, BK=16,
// 8x8 micro-tile, 256 threads.
// MODE 0: scatter half to q/k layout [b][comp][h][s][hd]
// MODE 2: scatter half to v layout   [b][h][s][hd]
// MODE 3: fp32 row-major C[m*N + n]
// ---------------------------------------------------------------------------
template <int MODE, typename OutT>
__global__ __launch_bounds__(256) void gemm_kernel(
    const float* __restrict__ A, const float* __restrict__ Bm,
    OutT* __restrict__ C, int N) {
  __shared__ float As[16][132];  // A tile transposed: As[k][m]
  __shared__ float Bs[16][132];  // B tile natural:   Bs[k][n]
  const int t = threadIdx.x;
  const int tx = t & 15, ty = t >> 4;
  const int m0 = blockIdx.y * 128, n0 = blockIdx.x * 128;
  const int K = 1024;

  float acc[8][8];
#pragma unroll
  for (int i = 0; i < 8; ++i)
#pragma unroll
    for (int j = 0; j < 8; ++j) acc[i][j] = 0.f;

  const int ar = t >> 2;          // 0..63
  const int ac4 = (t & 3) << 2;   // 0,4,8,12
  const int bkr = t >> 5;         // 0..7
  const int bn4 = (t & 31) << 2;  // 0..124

  for (int k0 = 0; k0 < K; k0 += 16) {
#pragma unroll
    for (int q = 0; q < 2; ++q) {
      int row = ar + 64 * q;
      float4 av = *(const float4*)(A + (size_t)(m0 + row) * K + k0 + ac4);
      As[ac4 + 0][row] = av.x;
      As[ac4 + 1][row] = av.y;
      As[ac4 + 2][row] = av.z;
      As[ac4 + 3][row] = av.w;
    }
#pragma unroll
    for (int q = 0; q < 2; ++q) {
      int kr = bkr + 8 * q;
      *(float4*)&Bs[kr][bn4] =
          *(const float4*)(Bm + (size_t)(k0 + kr) * N + n0 + bn4);
    }
    __syncthreads();
#pragma unroll
    for (int kk = 0; kk < 16; ++kk) {
      float a[8], b[8];
      *(float4*)(a) = *(const float4*)&As[kk][ty * 8];
      *(float4*)(a + 4) = *(const float4*)&As[kk][ty * 8 + 4];
      *(float4*)(b) = *(const float4*)&Bs[kk][tx * 8];
      *(float4*)(b + 4) = *(const float4*)&Bs[kk][tx * 8 + 4];
#pragma unroll
      for (int i = 0; i < 8; ++i)
#pragma unroll
        for (int j = 0; j < 8; ++j) acc[i][j] += a[i] * b[j];
    }
    __syncthreads();
  }

#pragma unroll
  for (int i = 0; i < 8; ++i) {
    int m = m0 + ty * 8 + i;
    int bb = m >> 11, s = m & 2047;  // S_LEN = 2048
    int col0 = n0 + tx * 8;
    if (MODE == 3) {
      float* p = (float*)C + (size_t)m * N + col0;
      *(float4*)p = make_float4(acc[i][0], acc[i][1], acc[i][2], acc[i][3]);
      *(float4*)(p + 4) = make_float4(acc[i][4], acc[i][5], acc[i][6], acc[i][7]);
    } else {
      __half hv[8];
#pragma unroll
      for (int j = 0; j < 8; ++j) hv[j] = __float2half(acc[i][j]);
      __half* p;
      if (MODE == 0) {
        int comp = col0 >> 10, rem = col0 & 1023;
        int h = rem >> 6, hd = rem & 63;
        p = (__half*)C +
            (((size_t)(bb * 2 + comp) * NH + h) * S_LEN + s) * HD + hd;
      } else {  // MODE 2 (v)
        int h = col0 >> 6, hd = col0 & 63;
        p = (__half*)C + (((size_t)bb * NH + h) * S_LEN + s) * HD + hd;
      }
      *(float4*)p = *(float4*)hv;  // 8 halves, 16B aligned (hd multiple of 8)
    }
  }
}

// ---------------------------------------------------------------------------
// RoPE in place over q_h and k_h (contiguous, identical layout), fp16 storage,
// fp32 math. One thread per (row, freq-pair); rows of 64 halves; pair (p,p+32).
// ---------------------------------------------------------------------------
__global__ __launch_bounds__(256) void rope_kernel(__half* __restrict__ buf) {
  size_t idx = (size_t)blockIdx.x * 256 + threadIdx.x;  // 8,388,608 pairs
  int p = (int)(idx & 31);
  size_t row = idx >> 5;
  int s = (int)(row & 2047);
  __half* base = buf + row * 64;
  float x1 = __half2float(base[p]), x2 = __half2float(base[p + 32]);
  float inv = expf(-0.28782313662425574f * (float)p);  // 10000^(-p/32)
  float ang = (float)s * inv;
  float sn, cs;
  sincosf(ang, &sn, &cs);
  base[p] = __float2half(x1 * cs - x2 * sn);
  base[p + 32] = __float2half(x2 * cs + x1 * sn);
}

// ---------------------------------------------------------------------------
// Differential attention. Block = 256 threads = one (b,h) x 64-query tile.
// Unnormalized exp accumulation for both streams (scores*scale ~ N(0,1), no
// overflow), epilogue: out = O1/l1 - lam * O2/l2, written straight to d_out.
// ---------------------------------------------------------------------------
__global__ __launch_bounds__(256) void attn_kernel(
    const __half* __restrict__ q_h, const __half* __restrict__ k_h,
    const __half* __restrict__ v_h, float* __restrict__ out,
    const float* __restrict__ lq1, const float* __restrict__ lk1,
    const float* __restrict__ lq2, const float* __restrict__ lk2,
    const float* __restrict__ lam_init_p) {
  __shared__ float Qt1[64][64], Qt2[64][64];  // [hd][r]
  __shared__ float Kt1[64][64], Kt2[64][64];  // [hd][c]
  __shared__ float Vs[64][64];                // [c][d]
  __shared__ float Pt1[64][64], Pt2[64][64];  // [c][r]
  __shared__ float l1a[64], l2a[64];

  const int t = threadIdx.x;
  const int tx = t & 15, ty = t >> 4;
  const int qt = blockIdx.x;  // 0..31 query tiles
  const int bh = blockIdx.y;  // 0..31
  const int b = bh >> 4, h = bh & 15;

  const float lam0 = lam_init_p[0];
  const float lam = expf(lq1[h] * lk1[h]) - expf(lq2[h] * lk2[h]) + lam0;

  const size_t c1_off = ((size_t)(b * 2 + 0) * NH + h) * S_LEN * HD;
  const size_t c2_off = ((size_t)(b * 2 + 1) * NH + h) * S_LEN * HD;
  const size_t v_off = ((size_t)b * NH + h) * S_LEN * HD;

  if (t < 64) {
    l1a[t] = 0.f;
    l2a[t] = 0.f;
  }

  // Load Q tiles transposed: Qt[hd][r]. Thread: r = t>>3 (+32*rr), c8=(t&7)*8.
  const int lr = t >> 3, lc8 = (t & 7) << 3;
#pragma unroll
  for (int rr = 0; rr < 2; ++rr) {
    int r = lr + 32 * rr;
    size_t g = (size_t)(qt * 64 + r) * HD + lc8;
    float f1[8], f2[8];
    half8_to_float8(q_h + c1_off + g, f1);
    half8_to_float8(q_h + c2_off + g, f2);
#pragma unroll
    for (int j = 0; j < 8; ++j) {
      Qt1[lc8 + j][r] = f1[j];
      Qt2[lc8 + j][r] = f2[j];
    }
  }

  float O1[4][4] = {{0.f}}, O2[4][4] = {{0.f}};
  float l1p[4] = {0.f, 0.f, 0.f, 0.f}, l2p[4] = {0.f, 0.f, 0.f, 0.f};

  for (int kt = 0; kt < 32; ++kt) {
    __syncthreads();  // prev PV done; initial Q/l writes visible at kt=0
#pragma unroll
    for (int rr = 0; rr < 2; ++rr) {
      int r = lr + 32 * rr;  // key row within tile
      size_t g = (size_t)(kt * 64 + r) * HD + lc8;
      float f1[8], f2[8], fv[8];
      half8_to_float8(k_h + c1_off + g, f1);
      half8_to_float8(k_h + c2_off + g, f2);
      half8_to_float8(v_h + v_off + g, fv);
#pragma unroll
      for (int j = 0; j < 8; ++j) {
        Kt1[lc8 + j][r] = f1[j];
        Kt2[lc8 + j][r] = f2[j];
      }
      *(float4*)&Vs[r][lc8] = *(float4*)fv;
      *(float4*)&Vs[r][lc8 + 4] = *(float4*)(fv + 4);
    }
    __syncthreads();

    // Scores: thread owns c = 4*ty+i, r = 4*tx+j
    float s1[4][4] = {{0.f}}, s2[4][4] = {{0.f}};
#pragma unroll 4
    for (int kk = 0; kk < 64; ++kk) {
      float kq1[4], kq2[4], qq1[4], qq2[4];
      *(float4*)kq1 = *(const float4*)&Kt1[kk][ty * 4];
      *(float4*)kq2 = *(const float4*)&Kt2[kk][ty * 4];
      *(float4*)qq1 = *(const float4*)&Qt1[kk][tx * 4];
      *(float4*)qq2 = *(const float4*)&Qt2[kk][tx * 4];
#pragma unroll
      for (int i = 0; i < 4; ++i)
#pragma unroll
        for (int j = 0; j < 4; ++j) {
          s1[i][j] += kq1[i] * qq1[j];
          s2[i][j] += kq2[i] * qq2[j];
        }
    }
#pragma unroll
    for (int i = 0; i < 4; ++i) {
      float p1[4], p2[4];
#pragma unroll
      for (int j = 0; j < 4; ++j) {
        p1[j] = __expf(s1[i][j] * SCALE);
        p2[j] = __expf(s2[i][j] * SCALE);
        l1p[j] += p1[j];
        l2p[j] += p2[j];
      }
      *(float4*)&Pt1[ty * 4 + i][tx * 4] = *(float4*)p1;
      *(float4*)&Pt2[ty * 4 + i][tx * 4] = *(float4*)p2;
    }
    __syncthreads();

    // PV: thread owns r = 4*ty+i, d = 4*tx+j
#pragma unroll 4
    for (int cc = 0; cc < 64; ++cc) {
      float pp1[4], pp2[4], vv[4];
      *(float4*)pp1 = *(const float4*)&Pt1[cc][ty * 4];
      *(float4*)pp2 = *(const float4*)&Pt2[cc][ty * 4];
      *(float4*)vv = *(const float4*)&Vs[cc][tx * 4];
#pragma unroll
      for (int i = 0; i < 4; ++i)
#pragma unroll
        for (int j = 0; j < 4; ++j) {
          O1[i][j] += pp1[i] * vv[j];
          O2[i][j] += pp2[i] * vv[j];
        }
    }
  }

  // Reduce row sums (score phase owned r = 4*tx+j)
#pragma unroll
  for (int j = 0; j < 4; ++j) {
    atomicAdd(&l1a[tx * 4 + j], l1p[j]);
    atomicAdd(&l2a[tx * 4 + j], l2p[j]);
  }
  __syncthreads();

  // Epilogue: out[(b*S+s)*THD + h*HD + d]  (row-major [b][s][h][hd])
#pragma unroll
  for (int i = 0; i < 4; ++i) {
    int r = ty * 4 + i;
    float il1 = 1.f / l1a[r];
    float il2 = lam / l2a[r];
    float4 o;
    o.x = O1[i][0] * il1 - O2[i][0] * il2;
    o.y = O1[i][1] * il1 - O2[i][1] * il2;
    o.z = O1[i][2] * il1 - O2[i][2] * il2;
    o.w = O1[i][3] * il1 - O2[i][3] * il2;
    int s = qt * 64 + r;
    *(float4*)(out + ((size_t)(b * S_LEN + s)) * THD_ + h * HD + tx * 4) = o;
  }
}

// ---------------------------------------------------------------------------
// GroupNorm over 64-elem head groups, src -> dst, fused * (1 - lambda_init).
// One wave per group, 4 groups per 256-thread block.
// ---------------------------------------------------------------------------
__global__ __launch_bounds__(256) void gn_kernel(
    const float* __restrict__ src, float* __restrict__ dst,
    const float* __restrict__ gw, const float* __restrict__ gb,
    const float* __restrict__ lam_init_p) {
  int g = blockIdx.x * 4 + (threadIdx.x >> 6);
  int lane = threadIdx.x & 63;
  float v = src[(size_t)g * 64 + lane];
  float s = v, sq = v * v;
#pragma unroll
  for (int off = 32; off; off >>= 1) {
    s += __shfl_xor(s, off);
    sq += __shfl_xor(sq, off);
  }
  float mean = s * (1.f / 64.f);
  float var = sq * (1.f / 64.f) - mean * mean;
  float rs = rsqrtf(var + 1e-5f);
  int h = g & 15;  // g = (b*S + s)*NH + h
  float w = gw[h * 64 + lane], bb = gb[h * 64 + lane];
  dst[(size_t)g * 64 + lane] =
      ((v - mean) * rs * w + bb) * (1.f - lam_init_p[0]);
}

// ---------------------------------------------------------------------------
extern "C" void kernel_launch(void* const* d_in, const int* in_sizes, int n_in,
                              void* d_out, int out_size, void* d_ws,
                              size_t ws_size, hipStream_t stream) {
  const float* x = (const float*)d_in[0];
  const float* Wq = (const float*)d_in[1];
  const float* Wk = (const float*)d_in[2];
  const float* Wv = (const float*)d_in[3];
  const float* Wo = (const float*)d_in[4];
  const float* lq1 = (const float*)d_in[5];
  const float* lk1 = (const float*)d_in[6];
  const float* lq2 = (const float*)d_in[7];
  const float* lk2 = (const float*)d_in[8];
  const float* lam_init = (const float*)d_in[9];
  const float* gnw = (const float*)d_in[10];
  const float* gnb = (const float*)d_in[11];
  float* out = (float*)d_out;

  __half* q_h = (__half*)d_ws;                  // 8,388,608 halves
  __half* k_h = q_h + 8388608;                  // 8,388,608 halves
  __half* v_h = k_h + 8388608;                  // 4,194,304 halves
  float* gn_out = (float*)d_ws;                 // reuses dead q region

  dim3 blk(256);
  // QKV projections (fused scatter into attention layouts, fp16 storage)
  gemm_kernel<0, __half><<<dim3(16, 32), blk, 0, stream>>>(x, Wq, q_h, 2048);
  gemm_kernel<0, __half><<<dim3(16, 32), blk, 0, stream>>>(x, Wk, k_h, 2048);
  gemm_kernel<2, __half><<<dim3(8, 32), blk, 0, stream>>>(x, Wv, v_h, 1024);
  // RoPE over q and k (contiguous halves, 8,388,608 rotation pairs)
  rope_kernel<<<32768, blk, 0, stream>>>(q_h);
  // Differential attention -> d_out (row-major [b][s][h][hd])
  attn_kernel<<<dim3(32, 32), blk, 0, stream>>>(q_h, k_h, v_h, out, lq1, lk1,
                                                lq2, lk2, lam_init);
  // GroupNorm (+ (1-lambda_init) scale): d_out -> gn_out
  gn_kernel<<<16384, blk, 0, stream>>>(out, gn_out, gnw, gnb, lam_init);
  // Output projection: gn_out @ Wo -> d_out
  gemm_kernel<3, float><<<dim3(8, 32), blk, 0, stream>>>(gn_out, Wo, out, 1024);
}

// Round 3
// 1062.498 us; speedup vs baseline: 1.8582x; 1.8582x over previous
//
#include <hip/hip_runtime.h>
#include <hip/hip_fp16.h>
#include <math.h>

#define B_SZ   2
#define S_LEN  2048
#define D_MODEL 1024
#define NH     16
#define HD     64
#define THD_   1024
// exp(s*0.125) = exp2(s * 0.125 * log2(e))
#define SCALE_LOG2E 0.18033688011112042f

typedef __fp16 f16x8 __attribute__((ext_vector_type(8)));
typedef __fp16 f16x4 __attribute__((ext_vector_type(4)));
typedef float f32x4 __attribute__((ext_vector_type(4)));

// ws layout:
//   q_h : __half [b][comp][h][s][hd]  8,388,608 elems @ 0          (16.78 MB)
//   k_h : __half same                 8,388,608 elems @ 16,777,216 (16.78 MB)
//   vt_h: __half [b][h][hd][s]        4,194,304 elems @ 33,554,432 ( 8.39 MB)
//   gn_out : float 4,194,304 elems @ 0 (reuses dead q region after attention)
// total ws use: 41,943,040 bytes.

// ---------------------------------------------------------------------------
// GEMM: C = A(4096 x 1024) * B(1024 x N), fp32 A/B, 128x128 tile, BK=16,
// 8x8 micro-tile, 256 threads.
// MODE 0: scatter half to q/k layout [b][comp][h][s][hd]
// MODE 3: fp32 row-major C[m*N + n]
// MODE 4: scatter half TRANSPOSED to v^T layout [b][h][hd][s]
// ---------------------------------------------------------------------------
template <int MODE, typename OutT>
__global__ __launch_bounds__(256) void gemm_kernel(
    const float* __restrict__ A, const float* __restrict__ Bm,
    OutT* __restrict__ C, int N) {
  __shared__ float As[16][132];  // A tile transposed: As[k][m]
  __shared__ float Bs[16][132];  // B tile natural:   Bs[k][n]
  const int t = threadIdx.x;
  const int tx = t & 15, ty = t >> 4;
  const int m0 = blockIdx.y * 128, n0 = blockIdx.x * 128;
  const int K = 1024;

  float acc[8][8];
#pragma unroll
  for (int i = 0; i < 8; ++i)
#pragma unroll
    for (int j = 0; j < 8; ++j) acc[i][j] = 0.f;

  const int ar = t >> 2;          // 0..63
  const int ac4 = (t & 3) << 2;   // 0,4,8,12
  const int bkr = t >> 5;         // 0..7
  const int bn4 = (t & 31) << 2;  // 0..124

  for (int k0 = 0; k0 < K; k0 += 16) {
#pragma unroll
    for (int q = 0; q < 2; ++q) {
      int row = ar + 64 * q;
      float4 av = *(const float4*)(A + (size_t)(m0 + row) * K + k0 + ac4);
      As[ac4 + 0][row] = av.x;
      As[ac4 + 1][row] = av.y;
      As[ac4 + 2][row] = av.z;
      As[ac4 + 3][row] = av.w;
    }
#pragma unroll
    for (int q = 0; q < 2; ++q) {
      int kr = bkr + 8 * q;
      *(float4*)&Bs[kr][bn4] =
          *(const float4*)(Bm + (size_t)(k0 + kr) * N + n0 + bn4);
    }
    __syncthreads();
#pragma unroll
    for (int kk = 0; kk < 16; ++kk) {
      float a[8], b[8];
      *(float4*)(a) = *(const float4*)&As[kk][ty * 8];
      *(float4*)(a + 4) = *(const float4*)&As[kk][ty * 8 + 4];
      *(float4*)(b) = *(const float4*)&Bs[kk][tx * 8];
      *(float4*)(b + 4) = *(const float4*)&Bs[kk][tx * 8 + 4];
#pragma unroll
      for (int i = 0; i < 8; ++i)
#pragma unroll
        for (int j = 0; j < 8; ++j) acc[i][j] += a[i] * b[j];
    }
    __syncthreads();
  }

  if (MODE == 4) {
    // V^T scatter: for each col j, 8 consecutive tokens -> 8 halves = 16B
    const int s0 = (m0 + ty * 8) & 2047;
    const int bb = (m0 + ty * 8) >> 11;
#pragma unroll
    for (int j = 0; j < 8; ++j) {
      int col = n0 + tx * 8 + j;
      int h = col >> 6, hd = col & 63;
      __half hv[8];
#pragma unroll
      for (int i = 0; i < 8; ++i) hv[i] = __float2half(acc[i][j]);
      __half* p =
          (__half*)C + (((size_t)bb * NH + h) * HD + hd) * S_LEN + s0;
      *(float4*)p = *(float4*)hv;
    }
    return;
  }

#pragma unroll
  for (int i = 0; i < 8; ++i) {
    int m = m0 + ty * 8 + i;
    int bb = m >> 11, s = m & 2047;
    int col0 = n0 + tx * 8;
    if (MODE == 3) {
      float* p = (float*)C + (size_t)m * N + col0;
      *(float4*)p = make_float4(acc[i][0], acc[i][1], acc[i][2], acc[i][3]);
      *(float4*)(p + 4) = make_float4(acc[i][4], acc[i][5], acc[i][6], acc[i][7]);
    } else {  // MODE 0 (q/k)
      __half hv[8];
#pragma unroll
      for (int j = 0; j < 8; ++j) hv[j] = __float2half(acc[i][j]);
      int comp = col0 >> 10, rem = col0 & 1023;
      int h = rem >> 6, hd = rem & 63;
      __half* p = (__half*)C +
                  (((size_t)(bb * 2 + comp) * NH + h) * S_LEN + s) * HD + hd;
      *(float4*)p = *(float4*)hv;
    }
  }
}

// ---------------------------------------------------------------------------
// RoPE in place over q_h and k_h (contiguous, identical layout), fp16 storage,
// fp32 math. One thread per (row, freq-pair); rows of 64 halves; pair (p,p+32).
// ---------------------------------------------------------------------------
__global__ __launch_bounds__(256) void rope_kernel(__half* __restrict__ buf) {
  size_t idx = (size_t)blockIdx.x * 256 + threadIdx.x;  // 8,388,608 pairs
  int p = (int)(idx & 31);
  size_t row = idx >> 5;
  int s = (int)(row & 2047);
  __half* base = buf + row * 64;
  float x1 = __half2float(base[p]), x2 = __half2float(base[p + 32]);
  float inv = expf(-0.28782313662425574f * (float)p);  // 10000^(-p/32)
  float ang = (float)s * inv;
  float sn, cs;
  sincosf(ang, &sn, &cs);
  base[p] = __float2half(x1 * cs - x2 * sn);
  base[p + 32] = __float2half(x2 * cs + x1 * sn);
}

// ---------------------------------------------------------------------------
// Differential attention, MFMA (16x16x32 f16), barrier-free.
// Block = 256 threads = 4 waves; wave w owns 32 query rows of a 128-query
// tile for one (b,h). K-loop over 64-key tiles:
//   S^T = K . Q^T     (A = K frag from global, B = Q frag held in regs)
//   P   = exp2(S^T * c)  -> wave-private LDS, row-major [query][key]
//   O^T += V^T . P^T  (A = Vt frag from global, B = P frag from LDS)
// Unnormalized accumulation; epilogue: out = O1/l1 - lam*O2/l2.
// No __syncthreads anywhere (P buffers are wave-private).
// ---------------------------------------------------------------------------
__global__ __launch_bounds__(256) void attn_kernel(
    const __half* __restrict__ q_h, const __half* __restrict__ k_h,
    const __half* __restrict__ vt_h, float* __restrict__ out,
    const float* __restrict__ lq1, const float* __restrict__ lk1,
    const float* __restrict__ lq2, const float* __restrict__ lk2,
    const float* __restrict__ lam_init_p) {
  // [wave][stream][query 32][key 64 + pad 8] ; rows 144B (16B-aligned)
  __shared__ __half P_lds[4][2][32][72];

  const int t = threadIdx.x;
  const int w = t >> 6, lane = t & 63;
  const int quad = lane >> 4, lqi = lane & 15;
  const int qt = blockIdx.x;   // 0..15 (128-query tiles)
  const int bh = blockIdx.y;   // 0..31
  const int b = bh >> 4, h = bh & 15;

  const size_t c1 = ((size_t)(b * 2 + 0) * NH + h) * (size_t)S_LEN * HD;
  const size_t c2 = ((size_t)(b * 2 + 1) * NH + h) * (size_t)S_LEN * HD;
  const size_t vtb = ((size_t)b * NH + h) * (size_t)HD * S_LEN;
  const int q0 = qt * 128 + w * 32;

  // Q fragments (B-layout): lane holds Q[q0+nt*16+lqi][ks*32+quad*8 .. +7]
  f16x8 qf[2][2][2];  // [stream][nt][ks]
#pragma unroll
  for (int nt = 0; nt < 2; ++nt)
#pragma unroll
    for (int ks = 0; ks < 2; ++ks) {
      size_t a = (size_t)(q0 + nt * 16 + lqi) * HD + ks * 32 + quad * 8;
      qf[0][nt][ks] = *(const f16x8*)(q_h + c1 + a);
      qf[1][nt][ks] = *(const f16x8*)(q_h + c2 + a);
    }

  f32x4 O[2][4][2];  // [stream][mt(hd)][nt]
#pragma unroll
  for (int s = 0; s < 2; ++s)
#pragma unroll
    for (int mt = 0; mt < 4; ++mt)
#pragma unroll
      for (int nt = 0; nt < 2; ++nt) O[s][mt][nt] = (f32x4){0.f, 0.f, 0.f, 0.f};
  float lsum[2][2] = {{0.f, 0.f}, {0.f, 0.f}};  // [stream][nt]

  for (int kt = 0; kt < 32; ++kt) {
    const int k0 = kt * 64;
    // ---- scores + exp + P store ----
#pragma unroll
    for (int mt = 0; mt < 4; ++mt) {
      size_t ka0 = (size_t)(k0 + mt * 16 + lqi) * HD + quad * 8;
      f16x8 kf[2][2];  // [stream][ks]
      kf[0][0] = *(const f16x8*)(k_h + c1 + ka0);
      kf[0][1] = *(const f16x8*)(k_h + c1 + ka0 + 32);
      kf[1][0] = *(const f16x8*)(k_h + c2 + ka0);
      kf[1][1] = *(const f16x8*)(k_h + c2 + ka0 + 32);
#pragma unroll
      for (int str = 0; str < 2; ++str)
#pragma unroll
        for (int nt = 0; nt < 2; ++nt) {
          f32x4 s = (f32x4){0.f, 0.f, 0.f, 0.f};
          s = __builtin_amdgcn_mfma_f32_16x16x32_f16(kf[str][0],
                                                     qf[str][nt][0], s, 0, 0, 0);
          s = __builtin_amdgcn_mfma_f32_16x16x32_f16(kf[str][1],
                                                     qf[str][nt][1], s, 0, 0, 0);
          f16x4 p;
          float ls = 0.f;
#pragma unroll
          for (int i = 0; i < 4; ++i) {
            float e = exp2f(s[i] * SCALE_LOG2E);
            ls += e;
            p[i] = (__fp16)e;
          }
          lsum[str][nt] += ls;
          *(f16x4*)&P_lds[w][str][nt * 16 + lqi][mt * 16 + quad * 4] = p;
        }
    }
    // ---- PV ----
#pragma unroll
    for (int ks2 = 0; ks2 < 2; ++ks2) {
      f16x8 pf[2][2];  // [stream][nt]
#pragma unroll
      for (int str = 0; str < 2; ++str)
#pragma unroll
        for (int nt = 0; nt < 2; ++nt)
          pf[str][nt] = *(const f16x8*)&P_lds[w][str][nt * 16 + lqi]
                                             [ks2 * 32 + quad * 8];
#pragma unroll
      for (int mt = 0; mt < 4; ++mt) {
        f16x8 vf = *(const f16x8*)(vt_h + vtb + (size_t)(mt * 16 + lqi) * S_LEN +
                                   k0 + ks2 * 32 + quad * 8);
#pragma unroll
        for (int str = 0; str < 2; ++str)
#pragma unroll
          for (int nt = 0; nt < 2; ++nt)
            O[str][mt][nt] = __builtin_amdgcn_mfma_f32_16x16x32_f16(
                vf, pf[str][nt], O[str][mt][nt], 0, 0, 0);
      }
    }
  }

  // ---- epilogue ----
  const float lam0 = lam_init_p[0];
  const float lam = expf(lq1[h] * lk1[h]) - expf(lq2[h] * lk2[h]) + lam0;
#pragma unroll
  for (int str = 0; str < 2; ++str)
#pragma unroll
    for (int nt = 0; nt < 2; ++nt) {
      float v = lsum[str][nt];
      v += __shfl_xor(v, 16);
      v += __shfl_xor(v, 32);
      lsum[str][nt] = v;  // full key-sum for query nt*16+lqi
    }
#pragma unroll
  for (int nt = 0; nt < 2; ++nt) {
    float il1 = 1.f / lsum[0][nt];
    float il2 = lam / lsum[1][nt];
    int q = q0 + nt * 16 + lqi;
#pragma unroll
    for (int mt = 0; mt < 4; ++mt) {
      f32x4 o;
#pragma unroll
      for (int i = 0; i < 4; ++i)
        o[i] = O[0][mt][nt][i] * il1 - O[1][mt][nt][i] * il2;
      *(f32x4*)(out + ((size_t)(b * S_LEN + q)) * THD_ + h * HD + mt * 16 +
                quad * 4) = o;
    }
  }
}

// ---------------------------------------------------------------------------
// GroupNorm over 64-elem head groups, src -> dst, fused * (1 - lambda_init).
// ---------------------------------------------------------------------------
__global__ __launch_bounds__(256) void gn_kernel(
    const float* __restrict__ src, float* __restrict__ dst,
    const float* __restrict__ gw, const float* __restrict__ gb,
    const float* __restrict__ lam_init_p) {
  int g = blockIdx.x * 4 + (threadIdx.x >> 6);
  int lane = threadIdx.x & 63;
  float v = src[(size_t)g * 64 + lane];
  float s = v, sq = v * v;
#pragma unroll
  for (int off = 32; off; off >>= 1) {
    s += __shfl_xor(s, off);
    sq += __shfl_xor(sq, off);
  }
  float mean = s * (1.f / 64.f);
  float var = sq * (1.f / 64.f) - mean * mean;
  float rs = rsqrtf(var + 1e-5f);
  int h = g & 15;
  float w = gw[h * 64 + lane], bb = gb[h * 64 + lane];
  dst[(size_t)g * 64 + lane] =
      ((v - mean) * rs * w + bb) * (1.f - lam_init_p[0]);
}

// ---------------------------------------------------------------------------
extern "C" void kernel_launch(void* const* d_in, const int* in_sizes, int n_in,
                              void* d_out, int out_size, void* d_ws,
                              size_t ws_size, hipStream_t stream) {
  const float* x = (const float*)d_in[0];
  const float* Wq = (const float*)d_in[1];
  const float* Wk = (const float*)d_in[2];
  const float* Wv = (const float*)d_in[3];
  const float* Wo = (const float*)d_in[4];
  const float* lq1 = (const float*)d_in[5];
  const float* lk1 = (const float*)d_in[6];
  const float* lq2 = (const float*)d_in[7];
  const float* lk2 = (const float*)d_in[8];
  const float* lam_init = (const float*)d_in[9];
  const float* gnw = (const float*)d_in[10];
  const float* gnb = (const float*)d_in[11];
  float* out = (float*)d_out;

  __half* q_h = (__half*)d_ws;                  // 8,388,608 halves
  __half* k_h = q_h + 8388608;                  // 8,388,608 halves
  __half* vt_h = k_h + 8388608;                 // 4,194,304 halves [b][h][hd][s]
  float* gn_out = (float*)d_ws;                 // reuses dead q region

  dim3 blk(256);
  // QKV projections (fused scatter into attention layouts, fp16 storage)
  gemm_kernel<0, __half><<<dim3(16, 32), blk, 0, stream>>>(x, Wq, q_h, 2048);
  gemm_kernel<0, __half><<<dim3(16, 32), blk, 0, stream>>>(x, Wk, k_h, 2048);
  gemm_kernel<4, __half><<<dim3(8, 32), blk, 0, stream>>>(x, Wv, vt_h, 1024);
  // RoPE over q and k (contiguous halves, 8,388,608 rotation pairs)
  rope_kernel<<<32768, blk, 0, stream>>>(q_h);
  // Differential attention (MFMA) -> d_out (row-major [b][s][h][hd])
  attn_kernel<<<dim3(16, 32), blk, 0, stream>>>(q_h, k_h, vt_h, out, lq1, lk1,
                                                lq2, lk2, lam_init);
  // GroupNorm (+ (1-lambda_init) scale): d_out -> gn_out
  gn_kernel<<<16384, blk, 0, stream>>>(out, gn_out, gnw, gnb, lam_init);
  // Output projection: gn_out @ Wo -> d_out
  gemm_kernel<3, float><<<dim3(8, 32), blk, 0, stream>>>(gn_out, Wo, out, 1024);
}

// Round 4
// 486.767 us; speedup vs baseline: 4.0561x; 2.1828x over previous
//
#include <hip/hip_runtime.h>
#include <hip/hip_fp16.h>
#include <math.h>

#define NH     16
#define HD     64
#define S_LEN  2048
#define THD_   1024
// exp(s*0.125) = exp2(s * 0.125 * log2(e))
#define SCALE_LOG2E 0.18033688011112042f

typedef __fp16 f16x8 __attribute__((ext_vector_type(8)));
typedef __fp16 f16x4 __attribute__((ext_vector_type(4)));
typedef float  f32x4 __attribute__((ext_vector_type(4)));

// ws layout (halves unless noted), total 41,943,040 B (same as proven R2):
//   region A @ 0        : q_h  8,388,608   [b][comp][h][s][hd]
//   region B @ 8388608  : k_h  8,388,608   same layout
//   region C @ 16777216 : vt_h 4,194,304   [b][h][hd][s]
//   time-shared: WqT/WkT (fp16, [n][k]) live in C before v-GEMM writes it;
//   WoT @ A[0:1048576) and gn_h @ A[1048576:5242880) live in A after attn.

// ---------------------------------------------------------------------------
// Weight transpose+cast: W[k][n] fp32 (row-major, K=1024) -> WT[n][k] fp16.
// Lanes map to consecutive n -> coalesced reads; 16B writes scattered (ok).
// ---------------------------------------------------------------------------
__global__ __launch_bounds__(256) void wt_kernel(const float* __restrict__ W,
                                                 __half* __restrict__ WT,
                                                 int nmask, int nshift) {
  int id = blockIdx.x * 256 + threadIdx.x;
  int n = id & nmask;
  int k8 = (id >> nshift) * 8;
  int N = nmask + 1;
  f16x8 h;
#pragma unroll
  for (int j = 0; j < 8; ++j)
    h[j] = (__fp16)W[(size_t)(k8 + j) * N + n];
  *(f16x8*)(WT + (size_t)n * 1024 + k8) = h;
}

// ---------------------------------------------------------------------------
// fp16 MFMA GEMM: C = A(4096 x 1024) * B(1024 x N). 128x128 tile, BK=64,
// 4 waves each computing 64x64 (4x4 grid of 16x16x32 MFMA).
// MODE 0: A = x fp32 (cast in staging), B = WT fp16; epilogue fused RoPE,
//         scatter fp16 to [b][comp][h][s][hd]  (used for both Q and K)
// MODE 2: A = x fp32, B = raw Wv fp32 via coalesced column gather;
//         epilogue scatter fp16 to vt [b][h][hd][s]
// MODE 3: A = gn_h fp16, B = WoT fp16; epilogue fp32 row-major to d_out
// ---------------------------------------------------------------------------
template <int MODE>
__global__ __launch_bounds__(256) void mfma_gemm(const void* __restrict__ Ap,
                                                 const void* __restrict__ Bp,
                                                 void* __restrict__ Cp) {
  __shared__ __fp16 As[128][72];
  __shared__ __fp16 Bs[128][72];
  const int t = threadIdx.x;
  const int w = t >> 6, lane = t & 63;
  const int quad = lane >> 4, lqi = lane & 15;
  const int wm = (w >> 1) * 64, wn = (w & 1) * 64;
  const int n0 = blockIdx.x * 128, m0 = blockIdx.y * 128;

  f32x4 acc[4][4];
#pragma unroll
  for (int mt = 0; mt < 4; ++mt)
#pragma unroll
    for (int nt = 0; nt < 4; ++nt) acc[mt][nt] = (f32x4){0.f, 0.f, 0.f, 0.f};

  const int srow = t >> 3;         // staging row base (0..31)
  const int sc8 = (t & 7) * 8;     // staging col (halves)
  const int gn_ = t & 127;         // gather: n within tile
  const int gk0 = (t >> 7) * 8;    // gather: k base

  for (int k0 = 0; k0 < 1024; k0 += 64) {
    if (k0) __syncthreads();
    // ---- A staging ----
    if (MODE == 3) {
      const __half* A16 = (const __half*)Ap;
#pragma unroll
      for (int p = 0; p < 4; ++p) {
        int row = srow + 32 * p;
        *(f16x8*)&As[row][sc8] =
            *(const f16x8*)(A16 + (size_t)(m0 + row) * 1024 + k0 + sc8);
      }
    } else {
      const float* A32 = (const float*)Ap;
#pragma unroll
      for (int p = 0; p < 4; ++p) {
        int row = srow + 32 * p;
        const float* src = A32 + (size_t)(m0 + row) * 1024 + k0 + sc8;
        float4 u = *(const float4*)src;
        float4 v = *(const float4*)(src + 4);
        f16x8 h;
        h[0] = (__fp16)u.x; h[1] = (__fp16)u.y;
        h[2] = (__fp16)u.z; h[3] = (__fp16)u.w;
        h[4] = (__fp16)v.x; h[5] = (__fp16)v.y;
        h[6] = (__fp16)v.z; h[7] = (__fp16)v.w;
        *(f16x8*)&As[row][sc8] = h;
      }
    }
    // ---- B staging ----
    if (MODE == 2) {
      const float* B32 = (const float*)Bp;  // Wv row-major [k][1024]
#pragma unroll
      for (int p = 0; p < 4; ++p) {
        int kc = gk0 + 16 * p;  // 0..56
        f16x8 h;
#pragma unroll
        for (int j = 0; j < 8; ++j)
          h[j] = (__fp16)B32[(size_t)(k0 + kc + j) * 1024 + n0 + gn_];
        *(f16x8*)&Bs[gn_][kc] = h;
      }
    } else {
      const __half* B16 = (const __half*)Bp;  // WT [n][k]
#pragma unroll
      for (int p = 0; p < 4; ++p) {
        int row = srow + 32 * p;
        *(f16x8*)&Bs[row][sc8] =
            *(const f16x8*)(B16 + (size_t)(n0 + row) * 1024 + k0 + sc8);
      }
    }
    __syncthreads();
    // ---- MFMA ----
#pragma unroll
    for (int ks = 0; ks < 2; ++ks) {
      f16x8 af[4], bf[4];
#pragma unroll
      for (int mt = 0; mt < 4; ++mt)
        af[mt] = *(const f16x8*)&As[wm + mt * 16 + lqi][ks * 32 + quad * 8];
#pragma unroll
      for (int nt = 0; nt < 4; ++nt)
        bf[nt] = *(const f16x8*)&Bs[wn + nt * 16 + lqi][ks * 32 + quad * 8];
#pragma unroll
      for (int mt = 0; mt < 4; ++mt)
#pragma unroll
        for (int nt = 0; nt < 4; ++nt)
          acc[mt][nt] = __builtin_amdgcn_mfma_f32_16x16x32_f16(
              af[mt], bf[nt], acc[mt][nt], 0, 0, 0);
    }
  }

  // ---- epilogue ----
  // D mapping (verified R2): row m = quad*4+i (A rows), col n = lqi (B rows)
  const int b = m0 >> 11;
  const int s0 = (m0 & 2047) + wm + quad * 4;
  if (MODE == 0) {
    // wave owns cols [n0+wn, +64) = one (comp, head); rope pair (p, p+32)
    // is acc[mt][nt] vs acc[mt][nt+2]
    __half* dst = (__half*)Cp;
    const int col0 = n0 + wn;
    const int comp = col0 >> 10, hh = (col0 >> 6) & 15;
    __half* base = dst + ((size_t)(b * 2 + comp) * NH + hh) * (size_t)S_LEN * HD;
#pragma unroll
    for (int nt = 0; nt < 2; ++nt) {
      int p = nt * 16 + lqi;
      float inv = expf(-0.28782313662425574f * (float)p);  // 10000^(-p/32)
#pragma unroll
      for (int mt = 0; mt < 4; ++mt) {
#pragma unroll
        for (int i = 0; i < 4; ++i) {
          int s = s0 + mt * 16 + i;
          float sn, cs;
          sincosf((float)s * inv, &sn, &cs);
          float x1 = acc[mt][nt][i], x2 = acc[mt][nt + 2][i];
          base[(size_t)s * HD + p] = __float2half(x1 * cs - x2 * sn);
          base[(size_t)s * HD + p + 32] = __float2half(x2 * cs + x1 * sn);
        }
      }
    }
  } else if (MODE == 2) {
    __half* vt = (__half*)Cp;
    const int hh = (n0 + wn) >> 6;
#pragma unroll
    for (int nt = 0; nt < 4; ++nt) {
      int hd = nt * 16 + lqi;
      __half* base = vt + (((size_t)b * NH + hh) * HD + hd) * S_LEN;
#pragma unroll
      for (int mt = 0; mt < 4; ++mt) {
        f16x4 hv;
#pragma unroll
        for (int i = 0; i < 4; ++i) hv[i] = (__fp16)acc[mt][nt][i];
        *(f16x4*)(base + s0 + mt * 16) = hv;
      }
    }
  } else {
    float* Co = (float*)Cp;
#pragma unroll
    for (int mt = 0; mt < 4; ++mt)
#pragma unroll
      for (int i = 0; i < 4; ++i) {
        int m = m0 + wm + mt * 16 + quad * 4 + i;
#pragma unroll
        for (int nt = 0; nt < 4; ++nt)
          Co[(size_t)m * 1024 + n0 + wn + nt * 16 + lqi] = acc[mt][nt][i];
      }
  }
}

// ---------------------------------------------------------------------------
// Differential attention, MFMA (16x16x32 f16), barrier-free (unchanged R2).
// ---------------------------------------------------------------------------
__global__ __launch_bounds__(256) void attn_kernel(
    const __half* __restrict__ q_h, const __half* __restrict__ k_h,
    const __half* __restrict__ vt_h, float* __restrict__ out,
    const float* __restrict__ lq1, const float* __restrict__ lk1,
    const float* __restrict__ lq2, const float* __restrict__ lk2,
    const float* __restrict__ lam_init_p) {
  __shared__ __half P_lds[4][2][32][72];

  const int t = threadIdx.x;
  const int w = t >> 6, lane = t & 63;
  const int quad = lane >> 4, lqi = lane & 15;
  const int qt = blockIdx.x;   // 0..15 (128-query tiles)
  const int bh = blockIdx.y;   // 0..31
  const int b = bh >> 4, h = bh & 15;

  const size_t c1 = ((size_t)(b * 2 + 0) * NH + h) * (size_t)S_LEN * HD;
  const size_t c2 = ((size_t)(b * 2 + 1) * NH + h) * (size_t)S_LEN * HD;
  const size_t vtb = ((size_t)b * NH + h) * (size_t)HD * S_LEN;
  const int q0 = qt * 128 + w * 32;

  f16x8 qf[2][2][2];  // [stream][nt][ks]
#pragma unroll
  for (int nt = 0; nt < 2; ++nt)
#pragma unroll
    for (int ks = 0; ks < 2; ++ks) {
      size_t a = (size_t)(q0 + nt * 16 + lqi) * HD + ks * 32 + quad * 8;
      qf[0][nt][ks] = *(const f16x8*)(q_h + c1 + a);
      qf[1][nt][ks] = *(const f16x8*)(q_h + c2 + a);
    }

  f32x4 O[2][4][2];
#pragma unroll
  for (int s = 0; s < 2; ++s)
#pragma unroll
    for (int mt = 0; mt < 4; ++mt)
#pragma unroll
      for (int nt = 0; nt < 2; ++nt) O[s][mt][nt] = (f32x4){0.f, 0.f, 0.f, 0.f};
  float lsum[2][2] = {{0.f, 0.f}, {0.f, 0.f}};

  for (int kt = 0; kt < 32; ++kt) {
    const int k0 = kt * 64;
#pragma unroll
    for (int mt = 0; mt < 4; ++mt) {
      size_t ka0 = (size_t)(k0 + mt * 16 + lqi) * HD + quad * 8;
      f16x8 kf[2][2];
      kf[0][0] = *(const f16x8*)(k_h + c1 + ka0);
      kf[0][1] = *(const f16x8*)(k_h + c1 + ka0 + 32);
      kf[1][0] = *(const f16x8*)(k_h + c2 + ka0);
      kf[1][1] = *(const f16x8*)(k_h + c2 + ka0 + 32);
#pragma unroll
      for (int str = 0; str < 2; ++str)
#pragma unroll
        for (int nt = 0; nt < 2; ++nt) {
          f32x4 s = (f32x4){0.f, 0.f, 0.f, 0.f};
          s = __builtin_amdgcn_mfma_f32_16x16x32_f16(kf[str][0],
                                                     qf[str][nt][0], s, 0, 0, 0);
          s = __builtin_amdgcn_mfma_f32_16x16x32_f16(kf[str][1],
                                                     qf[str][nt][1], s, 0, 0, 0);
          f16x4 p;
          float ls = 0.f;
#pragma unroll
          for (int i = 0; i < 4; ++i) {
            float e = exp2f(s[i] * SCALE_LOG2E);
            ls += e;
            p[i] = (__fp16)e;
          }
          lsum[str][nt] += ls;
          *(f16x4*)&P_lds[w][str][nt * 16 + lqi][mt * 16 + quad * 4] = p;
        }
    }
#pragma unroll
    for (int ks2 = 0; ks2 < 2; ++ks2) {
      f16x8 pf[2][2];
#pragma unroll
      for (int str = 0; str < 2; ++str)
#pragma unroll
        for (int nt = 0; nt < 2; ++nt)
          pf[str][nt] = *(const f16x8*)&P_lds[w][str][nt * 16 + lqi]
                                             [ks2 * 32 + quad * 8];
#pragma unroll
      for (int mt = 0; mt < 4; ++mt) {
        f16x8 vf = *(const f16x8*)(vt_h + vtb + (size_t)(mt * 16 + lqi) * S_LEN +
                                   k0 + ks2 * 32 + quad * 8);
#pragma unroll
        for (int str = 0; str < 2; ++str)
#pragma unroll
          for (int nt = 0; nt < 2; ++nt)
            O[str][mt][nt] = __builtin_amdgcn_mfma_f32_16x16x32_f16(
                vf, pf[str][nt], O[str][mt][nt], 0, 0, 0);
      }
    }
  }

  const float lam0 = lam_init_p[0];
  const float lam = expf(lq1[h] * lk1[h]) - expf(lq2[h] * lk2[h]) + lam0;
#pragma unroll
  for (int str = 0; str < 2; ++str)
#pragma unroll
    for (int nt = 0; nt < 2; ++nt) {
      float v = lsum[str][nt];
      v += __shfl_xor(v, 16);
      v += __shfl_xor(v, 32);
      lsum[str][nt] = v;
    }
#pragma unroll
  for (int nt = 0; nt < 2; ++nt) {
    float il1 = 1.f / lsum[0][nt];
    float il2 = lam / lsum[1][nt];
    int q = q0 + nt * 16 + lqi;
#pragma unroll
    for (int mt = 0; mt < 4; ++mt) {
      f32x4 o;
#pragma unroll
      for (int i = 0; i < 4; ++i)
        o[i] = O[0][mt][nt][i] * il1 - O[1][mt][nt][i] * il2;
      *(f32x4*)(out + ((size_t)(b * S_LEN + q)) * THD_ + h * HD + mt * 16 +
                quad * 4) = o;
    }
  }
}

// ---------------------------------------------------------------------------
// GroupNorm over 64-elem head groups, d_out fp32 -> gn_h fp16,
// fused * (1 - lambda_init).
// ---------------------------------------------------------------------------
__global__ __launch_bounds__(256) void gn_kernel(
    const float* __restrict__ src, __half* __restrict__ dst,
    const float* __restrict__ gw, const float* __restrict__ gb,
    const float* __restrict__ lam_init_p) {
  int g = blockIdx.x * 4 + (threadIdx.x >> 6);
  int lane = threadIdx.x & 63;
  float v = src[(size_t)g * 64 + lane];
  float s = v, sq = v * v;
#pragma unroll
  for (int off = 32; off; off >>= 1) {
    s += __shfl_xor(s, off);
    sq += __shfl_xor(sq, off);
  }
  float mean = s * (1.f / 64.f);
  float var = sq * (1.f / 64.f) - mean * mean;
  float rs = rsqrtf(var + 1e-5f);
  int h = g & 15;
  float w = gw[h * 64 + lane], bb = gb[h * 64 + lane];
  dst[(size_t)g * 64 + lane] =
      __float2half(((v - mean) * rs * w + bb) * (1.f - lam_init_p[0]));
}

// ---------------------------------------------------------------------------
extern "C" void kernel_launch(void* const* d_in, const int* in_sizes, int n_in,
                              void* d_out, int out_size, void* d_ws,
                              size_t ws_size, hipStream_t stream) {
  const float* x = (const float*)d_in[0];
  const float* Wq = (const float*)d_in[1];
  const float* Wk = (const float*)d_in[2];
  const float* Wv = (const float*)d_in[3];
  const float* Wo = (const float*)d_in[4];
  const float* lq1 = (const float*)d_in[5];
  const float* lk1 = (const float*)d_in[6];
  const float* lq2 = (const float*)d_in[7];
  const float* lk2 = (const float*)d_in[8];
  const float* lam_init = (const float*)d_in[9];
  const float* gnw = (const float*)d_in[10];
  const float* gnb = (const float*)d_in[11];
  float* out = (float*)d_out;

  __half* q_h = (__half*)d_ws;         // region A
  __half* k_h = q_h + 8388608;         // region B
  __half* vt_h = k_h + 8388608;        // region C
  __half* WqT = vt_h;                  // C[0 : 2097152)   (dead after k-GEMM)
  __half* WkT = vt_h + 2097152;        // C[2097152 : 4194304)
  __half* WoT = q_h;                   // A[0 : 1048576)   (q dead after attn)
  __half* gn_h = q_h + 1048576;        // A[1048576 : 5242880)

  dim3 blk(256);
  // weight transposes (fp32 -> fp16 [n][k])
  wt_kernel<<<1024, blk, 0, stream>>>(Wq, WqT, 2047, 11);
  wt_kernel<<<1024, blk, 0, stream>>>(Wk, WkT, 2047, 11);
  // projections (MFMA, fused RoPE for q/k)
  mfma_gemm<0><<<dim3(16, 32), blk, 0, stream>>>(x, WqT, q_h);
  mfma_gemm<0><<<dim3(16, 32), blk, 0, stream>>>(x, WkT, k_h);
  mfma_gemm<2><<<dim3(8, 32), blk, 0, stream>>>(x, Wv, vt_h);
  // differential attention -> d_out
  attn_kernel<<<dim3(16, 32), blk, 0, stream>>>(q_h, k_h, vt_h, out, lq1, lk1,
                                                lq2, lk2, lam_init);
  // Wo transpose into dead q region, then GroupNorm, then output projection
  wt_kernel<<<512, blk, 0, stream>>>(Wo, WoT, 1023, 10);
  gn_kernel<<<16384, blk, 0, stream>>>(out, gn_h, gnw, gnb, lam_init);
  mfma_gemm<3><<<dim3(8, 32), blk, 0, stream>>>(gn_h, WoT, out);
}

// Round 5
// 469.670 us; speedup vs baseline: 4.2037x; 1.0364x over previous
//
#include <hip/hip_runtime.h>
#include <hip/hip_fp16.h>
#include <math.h>

#define NH     16
#define HD     64
#define S_LEN  2048
#define THD_   1024
// exp(s*0.125) = exp2(s * 0.125 * log2(e))
#define SCALE_LOG2E 0.18033688011112042f

typedef __fp16 f16x8 __attribute__((ext_vector_type(8)));
typedef __fp16 f16x4 __attribute__((ext_vector_type(4)));
typedef float  f32x4 __attribute__((ext_vector_type(4)));

// ws layout (halves unless noted), total 41,943,040 B (proven safe):
//   region A @ 0        : q_h  8,388,608   [b][comp][h][s][hd]
//   region B @ 8388608  : k_h  8,388,608   same layout
//   region C @ 16777216 : vt_h 4,194,304   [b][h][hd][s]
//   time-shared: WqT/WkT (fp16 [n][k]) live in C before v-GEMM writes it;
//   WoT @ A[0:1048576) and gn_h @ A[1048576:5242880) live in A after attn.

// ---------------------------------------------------------------------------
// Weight transpose+cast: W[k][n] fp32 (row-major, K=1024) -> WT[n][k] fp16.
// ---------------------------------------------------------------------------
__global__ __launch_bounds__(256) void wt_kernel(const float* __restrict__ W,
                                                 __half* __restrict__ WT,
                                                 int nmask, int nshift) {
  int id = blockIdx.x * 256 + threadIdx.x;
  int n = id & nmask;
  int k8 = (id >> nshift) * 8;
  int N = nmask + 1;
  f16x8 h;
#pragma unroll
  for (int j = 0; j < 8; ++j)
    h[j] = (__fp16)W[(size_t)(k8 + j) * N + n];
  *(f16x8*)(WT + (size_t)n * 1024 + k8) = h;
}

// ---------------------------------------------------------------------------
// fp16 MFMA GEMM: C = A(4096 x 1024) * B(1024 x N). 128m x 64n tile, BK=64.
// 4 waves; wave w computes rows [w*32, w*32+32) x all 64 cols
// (mt 0..1 x nt 0..3 grid of 16x16x32 MFMA).
// MODE 0: A = x fp32 (cast in staging), B = WT fp16; fused-RoPE epilogue,
//         scatter fp16 to [b][comp][h][s][hd]  (used for both Q and K)
// MODE 2: A = x fp32, B = raw Wv fp32 via coalesced column gather;
//         epilogue scatter fp16 to vt [b][h][hd][s]
// MODE 3: A = gn_h fp16, B = WoT fp16; epilogue fp32 row-major to d_out
// ---------------------------------------------------------------------------
template <int MODE>
__global__ __launch_bounds__(256) void mfma_gemm(const void* __restrict__ Ap,
                                                 const void* __restrict__ Bp,
                                                 void* __restrict__ Cp) {
  __shared__ __fp16 As[128][72];
  __shared__ __fp16 Bs[64][72];
  const int t = threadIdx.x;
  const int w = t >> 6, lane = t & 63;
  const int quad = lane >> 4, lqi = lane & 15;
  const int wm = w * 32;
  const int n0 = blockIdx.x * 64, m0 = blockIdx.y * 128;

  f32x4 acc[2][4];
#pragma unroll
  for (int mt = 0; mt < 2; ++mt)
#pragma unroll
    for (int nt = 0; nt < 4; ++nt) acc[mt][nt] = (f32x4){0.f, 0.f, 0.f, 0.f};

  const int srow = t >> 3;         // staging row base (0..31)
  const int sc8 = (t & 7) * 8;     // staging col (halves)
  const int gn_ = t & 63;          // gather: n within tile
  const int gk0 = (t >> 6) * 8;    // gather: k base (0,8,16,24)

  for (int k0 = 0; k0 < 1024; k0 += 64) {
    if (k0) __syncthreads();
    // ---- A staging ----
    if (MODE == 3) {
      const __half* A16 = (const __half*)Ap;
#pragma unroll
      for (int p = 0; p < 4; ++p) {
        int row = srow + 32 * p;
        *(f16x8*)&As[row][sc8] =
            *(const f16x8*)(A16 + (size_t)(m0 + row) * 1024 + k0 + sc8);
      }
    } else {
      const float* A32 = (const float*)Ap;
#pragma unroll
      for (int p = 0; p < 4; ++p) {
        int row = srow + 32 * p;
        const float* src = A32 + (size_t)(m0 + row) * 1024 + k0 + sc8;
        float4 u = *(const float4*)src;
        float4 v = *(const float4*)(src + 4);
        f16x8 h;
        h[0] = (__fp16)u.x; h[1] = (__fp16)u.y;
        h[2] = (__fp16)u.z; h[3] = (__fp16)u.w;
        h[4] = (__fp16)v.x; h[5] = (__fp16)v.y;
        h[6] = (__fp16)v.z; h[7] = (__fp16)v.w;
        *(f16x8*)&As[row][sc8] = h;
      }
    }
    // ---- B staging ----
    if (MODE == 2) {
      const float* B32 = (const float*)Bp;  // Wv row-major [k][1024]
#pragma unroll
      for (int p = 0; p < 2; ++p) {
        int kc = gk0 + 32 * p;
        f16x8 h;
#pragma unroll
        for (int j = 0; j < 8; ++j)
          h[j] = (__fp16)B32[(size_t)(k0 + kc + j) * 1024 + n0 + gn_];
        *(f16x8*)&Bs[gn_][kc] = h;
      }
    } else {
      const __half* B16 = (const __half*)Bp;  // WT [n][k]
      if (srow < 32) {  // all threads participate via 2 passes
#pragma unroll
        for (int p = 0; p < 2; ++p) {
          int row = srow + 32 * p;
          *(f16x8*)&Bs[row][sc8] =
              *(const f16x8*)(B16 + (size_t)(n0 + row) * 1024 + k0 + sc8);
        }
      }
    }
    __syncthreads();
    // ---- MFMA ----
#pragma unroll
    for (int ks = 0; ks < 2; ++ks) {
      f16x8 af[2], bf[4];
#pragma unroll
      for (int mt = 0; mt < 2; ++mt)
        af[mt] = *(const f16x8*)&As[wm + mt * 16 + lqi][ks * 32 + quad * 8];
#pragma unroll
      for (int nt = 0; nt < 4; ++nt)
        bf[nt] = *(const f16x8*)&Bs[nt * 16 + lqi][ks * 32 + quad * 8];
#pragma unroll
      for (int mt = 0; mt < 2; ++mt)
#pragma unroll
        for (int nt = 0; nt < 4; ++nt)
          acc[mt][nt] = __builtin_amdgcn_mfma_f32_16x16x32_f16(
              af[mt], bf[nt], acc[mt][nt], 0, 0, 0);
    }
  }

  // ---- epilogue ----
  // D mapping: row m = quad*4+i, col n = lqi (within each 16x16 tile)
  const int b = m0 >> 11;
  const int s0 = (m0 & 2047) + wm + quad * 4;
  if (MODE == 0) {
    // tile cols [n0, n0+64) = one (comp, head); rope pair (p, p+32) is
    // acc[mt][nt] vs acc[mt][nt+2]
    __half* dst = (__half*)Cp;
    const int comp = n0 >> 10, hh = (n0 >> 6) & 15;
    __half* base = dst + ((size_t)(b * 2 + comp) * NH + hh) * (size_t)S_LEN * HD;
#pragma unroll
    for (int nt = 0; nt < 2; ++nt) {
      int p = nt * 16 + lqi;
      float inv = expf(-0.28782313662425574f * (float)p);  // 10000^(-p/32)
#pragma unroll
      for (int mt = 0; mt < 2; ++mt) {
#pragma unroll
        for (int i = 0; i < 4; ++i) {
          int s = s0 + mt * 16 + i;
          float sn, cs;
          sincosf((float)s * inv, &sn, &cs);
          float x1 = acc[mt][nt][i], x2 = acc[mt][nt + 2][i];
          base[(size_t)s * HD + p] = __float2half(x1 * cs - x2 * sn);
          base[(size_t)s * HD + p + 32] = __float2half(x2 * cs + x1 * sn);
        }
      }
    }
  } else if (MODE == 2) {
    __half* vt = (__half*)Cp;
    const int hh = n0 >> 6;
#pragma unroll
    for (int nt = 0; nt < 4; ++nt) {
      int hd = nt * 16 + lqi;
      __half* base = vt + (((size_t)b * NH + hh) * HD + hd) * S_LEN;
#pragma unroll
      for (int mt = 0; mt < 2; ++mt) {
        f16x4 hv;
#pragma unroll
        for (int i = 0; i < 4; ++i) hv[i] = (__fp16)acc[mt][nt][i];
        *(f16x4*)(base + s0 + mt * 16) = hv;
      }
    }
  } else {
    float* Co = (float*)Cp;
#pragma unroll
    for (int mt = 0; mt < 2; ++mt)
#pragma unroll
      for (int i = 0; i < 4; ++i) {
        int m = m0 + wm + mt * 16 + quad * 4 + i;
#pragma unroll
        for (int nt = 0; nt < 4; ++nt)
          Co[(size_t)m * 1024 + n0 + nt * 16 + lqi] = acc[mt][nt][i];
      }
  }
}

// ---------------------------------------------------------------------------
// Differential attention, MFMA (16x16x32 f16), barrier-free.
// Block = ONE 64-lane wave owning 32 query rows for one (b,h); grid (64, 32)
// = 2048 blocks for occupancy (R3 profile: 512 blocks -> 11% occupancy,
// latency-bound with all pipes idle).
//   S^T = K . Q^T ; P = exp2(S^T*c) -> wave-private LDS [query][key]
//   O^T += V^T . P^T ; epilogue out = O1/l1 - lam*O2/l2.
// ---------------------------------------------------------------------------
__global__ __launch_bounds__(64) void attn_kernel(
    const __half* __restrict__ q_h, const __half* __restrict__ k_h,
    const __half* __restrict__ vt_h, float* __restrict__ out,
    const float* __restrict__ lq1, const float* __restrict__ lk1,
    const float* __restrict__ lq2, const float* __restrict__ lk2,
    const float* __restrict__ lam_init_p) {
  __shared__ __half P_lds[2][32][72];  // [stream][query][key+pad]

  const int lane = threadIdx.x;
  const int quad = lane >> 4, lqi = lane & 15;
  const int qt = blockIdx.x;   // 0..63 (32-query tiles)
  const int bh = blockIdx.y;   // 0..31
  const int b = bh >> 4, h = bh & 15;

  const size_t c1 = ((size_t)(b * 2 + 0) * NH + h) * (size_t)S_LEN * HD;
  const size_t c2 = ((size_t)(b * 2 + 1) * NH + h) * (size_t)S_LEN * HD;
  const size_t vtb = ((size_t)b * NH + h) * (size_t)HD * S_LEN;
  const int q0 = qt * 32;

  f16x8 qf[2][2][2];  // [stream][nt][ks]
#pragma unroll
  for (int nt = 0; nt < 2; ++nt)
#pragma unroll
    for (int ks = 0; ks < 2; ++ks) {
      size_t a = (size_t)(q0 + nt * 16 + lqi) * HD + ks * 32 + quad * 8;
      qf[0][nt][ks] = *(const f16x8*)(q_h + c1 + a);
      qf[1][nt][ks] = *(const f16x8*)(q_h + c2 + a);
    }

  f32x4 O[2][4][2];
#pragma unroll
  for (int s = 0; s < 2; ++s)
#pragma unroll
    for (int mt = 0; mt < 4; ++mt)
#pragma unroll
      for (int nt = 0; nt < 2; ++nt) O[s][mt][nt] = (f32x4){0.f, 0.f, 0.f, 0.f};
  float lsum[2][2] = {{0.f, 0.f}, {0.f, 0.f}};

  for (int kt = 0; kt < 32; ++kt) {
    const int k0 = kt * 64;
#pragma unroll
    for (int mt = 0; mt < 4; ++mt) {
      size_t ka0 = (size_t)(k0 + mt * 16 + lqi) * HD + quad * 8;
      f16x8 kf[2][2];
      kf[0][0] = *(const f16x8*)(k_h + c1 + ka0);
      kf[0][1] = *(const f16x8*)(k_h + c1 + ka0 + 32);
      kf[1][0] = *(const f16x8*)(k_h + c2 + ka0);
      kf[1][1] = *(const f16x8*)(k_h + c2 + ka0 + 32);
#pragma unroll
      for (int str = 0; str < 2; ++str)
#pragma unroll
        for (int nt = 0; nt < 2; ++nt) {
          f32x4 s = (f32x4){0.f, 0.f, 0.f, 0.f};
          s = __builtin_amdgcn_mfma_f32_16x16x32_f16(kf[str][0],
                                                     qf[str][nt][0], s, 0, 0, 0);
          s = __builtin_amdgcn_mfma_f32_16x16x32_f16(kf[str][1],
                                                     qf[str][nt][1], s, 0, 0, 0);
          f16x4 p;
          float ls = 0.f;
#pragma unroll
          for (int i = 0; i < 4; ++i) {
            float e = exp2f(s[i] * SCALE_LOG2E);
            ls += e;
            p[i] = (__fp16)e;
          }
          lsum[str][nt] += ls;
          *(f16x4*)&P_lds[str][nt * 16 + lqi][mt * 16 + quad * 4] = p;
        }
    }
#pragma unroll
    for (int ks2 = 0; ks2 < 2; ++ks2) {
      f16x8 pf[2][2];
#pragma unroll
      for (int str = 0; str < 2; ++str)
#pragma unroll
        for (int nt = 0; nt < 2; ++nt)
          pf[str][nt] =
              *(const f16x8*)&P_lds[str][nt * 16 + lqi][ks2 * 32 + quad * 8];
#pragma unroll
      for (int mt = 0; mt < 4; ++mt) {
        f16x8 vf = *(const f16x8*)(vt_h + vtb + (size_t)(mt * 16 + lqi) * S_LEN +
                                   k0 + ks2 * 32 + quad * 8);
#pragma unroll
        for (int str = 0; str < 2; ++str)
#pragma unroll
          for (int nt = 0; nt < 2; ++nt)
            O[str][mt][nt] = __builtin_amdgcn_mfma_f32_16x16x32_f16(
                vf, pf[str][nt], O[str][mt][nt], 0, 0, 0);
      }
    }
  }

  const float lam0 = lam_init_p[0];
  const float lam = expf(lq1[h] * lk1[h]) - expf(lq2[h] * lk2[h]) + lam0;
#pragma unroll
  for (int str = 0; str < 2; ++str)
#pragma unroll
    for (int nt = 0; nt < 2; ++nt) {
      float v = lsum[str][nt];
      v += __shfl_xor(v, 16);
      v += __shfl_xor(v, 32);
      lsum[str][nt] = v;
    }
#pragma unroll
  for (int nt = 0; nt < 2; ++nt) {
    float il1 = 1.f / lsum[0][nt];
    float il2 = lam / lsum[1][nt];
    int q = q0 + nt * 16 + lqi;
#pragma unroll
    for (int mt = 0; mt < 4; ++mt) {
      f32x4 o;
#pragma unroll
      for (int i = 0; i < 4; ++i)
        o[i] = O[0][mt][nt][i] * il1 - O[1][mt][nt][i] * il2;
      *(f32x4*)(out + ((size_t)(b * S_LEN + q)) * THD_ + h * HD + mt * 16 +
                quad * 4) = o;
    }
  }
}

// ---------------------------------------------------------------------------
// GroupNorm over 64-elem head groups, d_out fp32 -> gn_h fp16,
// fused * (1 - lambda_init).
// ---------------------------------------------------------------------------
__global__ __launch_bounds__(256) void gn_kernel(
    const float* __restrict__ src, __half* __restrict__ dst,
    const float* __restrict__ gw, const float* __restrict__ gb,
    const float* __restrict__ lam_init_p) {
  int g = blockIdx.x * 4 + (threadIdx.x >> 6);
  int lane = threadIdx.x & 63;
  float v = src[(size_t)g * 64 + lane];
  float s = v, sq = v * v;
#pragma unroll
  for (int off = 32; off; off >>= 1) {
    s += __shfl_xor(s, off);
    sq += __shfl_xor(sq, off);
  }
  float mean = s * (1.f / 64.f);
  float var = sq * (1.f / 64.f) - mean * mean;
  float rs = rsqrtf(var + 1e-5f);
  int h = g & 15;
  float w = gw[h * 64 + lane], bb = gb[h * 64 + lane];
  dst[(size_t)g * 64 + lane] =
      __float2half(((v - mean) * rs * w + bb) * (1.f - lam_init_p[0]));
}

// ---------------------------------------------------------------------------
extern "C" void kernel_launch(void* const* d_in, const int* in_sizes, int n_in,
                              void* d_out, int out_size, void* d_ws,
                              size_t ws_size, hipStream_t stream) {
  const float* x = (const float*)d_in[0];
  const float* Wq = (const float*)d_in[1];
  const float* Wk = (const float*)d_in[2];
  const float* Wv = (const float*)d_in[3];
  const float* Wo = (const float*)d_in[4];
  const float* lq1 = (const float*)d_in[5];
  const float* lk1 = (const float*)d_in[6];
  const float* lq2 = (const float*)d_in[7];
  const float* lk2 = (const float*)d_in[8];
  const float* lam_init = (const float*)d_in[9];
  const float* gnw = (const float*)d_in[10];
  const float* gnb = (const float*)d_in[11];
  float* out = (float*)d_out;

  __half* q_h = (__half*)d_ws;         // region A
  __half* k_h = q_h + 8388608;         // region B
  __half* vt_h = k_h + 8388608;        // region C
  __half* WqT = vt_h;                  // C[0 : 2097152)   (dead after k-GEMM)
  __half* WkT = vt_h + 2097152;        // C[2097152 : 4194304)
  __half* WoT = q_h;                   // A[0 : 1048576)   (q dead after attn)
  __half* gn_h = q_h + 1048576;        // A[1048576 : 5242880)

  dim3 blk(256);
  // weight transposes (fp32 -> fp16 [n][k])
  wt_kernel<<<1024, blk, 0, stream>>>(Wq, WqT, 2047, 11);
  wt_kernel<<<1024, blk, 0, stream>>>(Wk, WkT, 2047, 11);
  // projections (MFMA, fused RoPE for q/k); 128m x 64n tiles
  mfma_gemm<0><<<dim3(32, 32), blk, 0, stream>>>(x, WqT, q_h);
  mfma_gemm<0><<<dim3(32, 32), blk, 0, stream>>>(x, WkT, k_h);
  mfma_gemm<2><<<dim3(16, 32), blk, 0, stream>>>(x, Wv, vt_h);
  // differential attention -> d_out (1-wave blocks for occupancy)
  attn_kernel<<<dim3(64, 32), dim3(64), 0, stream>>>(
      q_h, k_h, vt_h, out, lq1, lk1, lq2, lk2, lam_init);
  // Wo transpose into dead q region, then GroupNorm, then output projection
  wt_kernel<<<512, blk, 0, stream>>>(Wo, WoT, 1023, 10);
  gn_kernel<<<16384, blk, 0, stream>>>(out, gn_h, gnw, gnb, lam_init);
  mfma_gemm<3><<<dim3(16, 32), blk, 0, stream>>>(gn_h, WoT, out);
}

// Round 6
// 424.977 us; speedup vs baseline: 4.6458x; 1.1052x over previous
//
#include <hip/hip_runtime.h>
#include <hip/hip_fp16.h>
#include <math.h>

#define NH     16
#define HD     64
#define S_LEN  2048
#define THD_   1024
// exp(s*0.125) = exp2(s * 0.125 * log2(e))
#define SCALE_LOG2E 0.18033688011112042f

typedef __fp16 f16x8 __attribute__((ext_vector_type(8)));
typedef __fp16 f16x4 __attribute__((ext_vector_type(4)));
typedef __fp16 f16x2 __attribute__((ext_vector_type(2)));
typedef float  f32x4 __attribute__((ext_vector_type(4)));

// ws layout (halves unless noted), total 41,943,040 B (proven safe):
//   region A @ 0        : q_h  8,388,608   [b][comp][h][s][hd]
//   region B @ 8388608  : k_h  8,388,608   same layout
//   region C @ 16777216 : vt_h 4,194,304   [b][h][hd][s]
//   time-shared: WqT/WkT (fp16 [n][k]) live in C before v-GEMM writes it;
//   WoT @ A[0:1048576) and gn_h @ A[1048576:5242880) live in A after attn.

// ---------------------------------------------------------------------------
// Weight transpose+cast: W[k][n] fp32 (row-major, K=1024) -> WT[n][k] fp16.
// ---------------------------------------------------------------------------
__global__ __launch_bounds__(256) void wt_kernel(const float* __restrict__ W,
                                                 __half* __restrict__ WT,
                                                 int nmask, int nshift) {
  int id = blockIdx.x * 256 + threadIdx.x;
  int n = id & nmask;
  int k8 = (id >> nshift) * 8;
  int N = nmask + 1;
  f16x8 h;
#pragma unroll
  for (int j = 0; j < 8; ++j)
    h[j] = (__fp16)W[(size_t)(k8 + j) * N + n];
  *(f16x8*)(WT + (size_t)n * 1024 + k8) = h;
}

// ---------------------------------------------------------------------------
// fp16 MFMA GEMM: C = A(4096 x 1024) * B(1024 x N). 128m x 64n tile, BK=64.
// 4 waves; wave w computes rows [w*32, w*32+32) x all 64 cols.
// MODE 0: A = x fp32 (cast in staging), B = WT fp16; fused-RoPE epilogue,
//         scatter fp16 to [b][comp][h][s][hd]  (used for both Q and K)
// MODE 2: A = x fp32, B = raw Wv fp32 via coalesced column gather;
//         epilogue scatter fp16 to vt [b][h][hd][s]
// MODE 3: A = gn_h fp16, B = WoT fp16; epilogue fp32 row-major to d_out
// ---------------------------------------------------------------------------
template <int MODE>
__global__ __launch_bounds__(256) void mfma_gemm(const void* __restrict__ Ap,
                                                 const void* __restrict__ Bp,
                                                 void* __restrict__ Cp) {
  __shared__ __fp16 As[128][72];
  __shared__ __fp16 Bs[64][72];
  const int t = threadIdx.x;
  const int w = t >> 6, lane = t & 63;
  const int quad = lane >> 4, lqi = lane & 15;
  const int wm = w * 32;
  const int n0 = blockIdx.x * 64, m0 = blockIdx.y * 128;

  f32x4 acc[2][4];
#pragma unroll
  for (int mt = 0; mt < 2; ++mt)
#pragma unroll
    for (int nt = 0; nt < 4; ++nt) acc[mt][nt] = (f32x4){0.f, 0.f, 0.f, 0.f};

  const int srow = t >> 3;         // staging row base (0..31)
  const int sc8 = (t & 7) * 8;     // staging col (halves)
  const int gn_ = t & 63;          // gather: n within tile
  const int gk0 = (t >> 6) * 8;    // gather: k base (0,8,16,24)

  for (int k0 = 0; k0 < 1024; k0 += 64) {
    if (k0) __syncthreads();
    // ---- A staging ----
    if (MODE == 3) {
      const __half* A16 = (const __half*)Ap;
#pragma unroll
      for (int p = 0; p < 4; ++p) {
        int row = srow + 32 * p;
        *(f16x8*)&As[row][sc8] =
            *(const f16x8*)(A16 + (size_t)(m0 + row) * 1024 + k0 + sc8);
      }
    } else {
      const float* A32 = (const float*)Ap;
#pragma unroll
      for (int p = 0; p < 4; ++p) {
        int row = srow + 32 * p;
        const float* src = A32 + (size_t)(m0 + row) * 1024 + k0 + sc8;
        float4 u = *(const float4*)src;
        float4 v = *(const float4*)(src + 4);
        f16x8 h;
        h[0] = (__fp16)u.x; h[1] = (__fp16)u.y;
        h[2] = (__fp16)u.z; h[3] = (__fp16)u.w;
        h[4] = (__fp16)v.x; h[5] = (__fp16)v.y;
        h[6] = (__fp16)v.z; h[7] = (__fp16)v.w;
        *(f16x8*)&As[row][sc8] = h;
      }
    }
    // ---- B staging ----
    if (MODE == 2) {
      const float* B32 = (const float*)Bp;  // Wv row-major [k][1024]
#pragma unroll
      for (int p = 0; p < 2; ++p) {
        int kc = gk0 + 32 * p;
        f16x8 h;
#pragma unroll
        for (int j = 0; j < 8; ++j)
          h[j] = (__fp16)B32[(size_t)(k0 + kc + j) * 1024 + n0 + gn_];
        *(f16x8*)&Bs[gn_][kc] = h;
      }
    } else {
      const __half* B16 = (const __half*)Bp;  // WT [n][k]
      if (srow < 32) {
#pragma unroll
        for (int p = 0; p < 2; ++p) {
          int row = srow + 32 * p;
          *(f16x8*)&Bs[row][sc8] =
              *(const f16x8*)(B16 + (size_t)(n0 + row) * 1024 + k0 + sc8);
        }
      }
    }
    __syncthreads();
    // ---- MFMA ----
#pragma unroll
    for (int ks = 0; ks < 2; ++ks) {
      f16x8 af[2], bf[4];
#pragma unroll
      for (int mt = 0; mt < 2; ++mt)
        af[mt] = *(const f16x8*)&As[wm + mt * 16 + lqi][ks * 32 + quad * 8];
#pragma unroll
      for (int nt = 0; nt < 4; ++nt)
        bf[nt] = *(const f16x8*)&Bs[nt * 16 + lqi][ks * 32 + quad * 8];
#pragma unroll
      for (int mt = 0; mt < 2; ++mt)
#pragma unroll
        for (int nt = 0; nt < 4; ++nt)
          acc[mt][nt] = __builtin_amdgcn_mfma_f32_16x16x32_f16(
              af[mt], bf[nt], acc[mt][nt], 0, 0, 0);
    }
  }

  // ---- epilogue ----
  const int b = m0 >> 11;
  const int s0 = (m0 & 2047) + wm + quad * 4;
  if (MODE == 0) {
    __half* dst = (__half*)Cp;
    const int comp = n0 >> 10, hh = (n0 >> 6) & 15;
    __half* base = dst + ((size_t)(b * 2 + comp) * NH + hh) * (size_t)S_LEN * HD;
#pragma unroll
    for (int nt = 0; nt < 2; ++nt) {
      int p = nt * 16 + lqi;
      float inv = expf(-0.28782313662425574f * (float)p);  // 10000^(-p/32)
#pragma unroll
      for (int mt = 0; mt < 2; ++mt) {
#pragma unroll
        for (int i = 0; i < 4; ++i) {
          int s = s0 + mt * 16 + i;
          float sn, cs;
          sincosf((float)s * inv, &sn, &cs);
          float x1 = acc[mt][nt][i], x2 = acc[mt][nt + 2][i];
          base[(size_t)s * HD + p] = __float2half(x1 * cs - x2 * sn);
          base[(size_t)s * HD + p + 32] = __float2half(x2 * cs + x1 * sn);
        }
      }
    }
  } else if (MODE == 2) {
    __half* vt = (__half*)Cp;
    const int hh = n0 >> 6;
#pragma unroll
    for (int nt = 0; nt < 4; ++nt) {
      int hd = nt * 16 + lqi;
      __half* base = vt + (((size_t)b * NH + hh) * HD + hd) * S_LEN;
#pragma unroll
      for (int mt = 0; mt < 2; ++mt) {
        f16x4 hv;
#pragma unroll
        for (int i = 0; i < 4; ++i) hv[i] = (__fp16)acc[mt][nt][i];
        *(f16x4*)(base + s0 + mt * 16) = hv;
      }
    }
  } else {
    float* Co = (float*)Cp;
#pragma unroll
    for (int mt = 0; mt < 2; ++mt)
#pragma unroll
      for (int i = 0; i < 4; ++i) {
        int m = m0 + wm + mt * 16 + quad * 4 + i;
#pragma unroll
        for (int nt = 0; nt < 4; ++nt)
          Co[(size_t)m * 1024 + n0 + nt * 16 + lqi] = acc[mt][nt][i];
      }
  }
}

// ---------------------------------------------------------------------------
// Differential attention, MFMA (16x16x32 f16), barrier-free, 1-wave blocks.
// R5 restructure: ALL 24 global loads (16 K + 8 V) issue at the TOP of each
// kt iteration (R4 interleaved them with consumers -> ~5 exposed vmcnt waits
// per kt; counters showed latency-bound: VALU 39%, MFMA 12%, HBM 6.6%).
// __launch_bounds__(64,2) gives the scheduler a 256-VGPR budget so it keeps
// the loads hoisted instead of sinking them to save registers.
// ---------------------------------------------------------------------------
__global__ __launch_bounds__(64, 2) void attn_kernel(
    const __half* __restrict__ q_h, const __half* __restrict__ k_h,
    const __half* __restrict__ vt_h, float* __restrict__ out,
    const float* __restrict__ lq1, const float* __restrict__ lk1,
    const float* __restrict__ lq2, const float* __restrict__ lk2,
    const float* __restrict__ lam_init_p) {
  __shared__ __half P_lds[2][32][72];  // [stream][query][key+pad]

  const int lane = threadIdx.x;
  const int quad = lane >> 4, lqi = lane & 15;
  const int qt = blockIdx.x;   // 0..63 (32-query tiles)
  const int bh = blockIdx.y;   // 0..31
  const int b = bh >> 4, h = bh & 15;

  const size_t c1 = ((size_t)(b * 2 + 0) * NH + h) * (size_t)S_LEN * HD;
  const size_t c2 = ((size_t)(b * 2 + 1) * NH + h) * (size_t)S_LEN * HD;
  const size_t vtb = ((size_t)b * NH + h) * (size_t)HD * S_LEN;
  const int q0 = qt * 32;

  f16x8 qf[2][2][2];  // [stream][nt][ks]
#pragma unroll
  for (int nt = 0; nt < 2; ++nt)
#pragma unroll
    for (int ks = 0; ks < 2; ++ks) {
      size_t a = (size_t)(q0 + nt * 16 + lqi) * HD + ks * 32 + quad * 8;
      qf[0][nt][ks] = *(const f16x8*)(q_h + c1 + a);
      qf[1][nt][ks] = *(const f16x8*)(q_h + c2 + a);
    }

  f32x4 O[2][4][2];
#pragma unroll
  for (int s = 0; s < 2; ++s)
#pragma unroll
    for (int mt = 0; mt < 4; ++mt)
#pragma unroll
      for (int nt = 0; nt < 2; ++nt) O[s][mt][nt] = (f32x4){0.f, 0.f, 0.f, 0.f};
  float lsum[2][2] = {{0.f, 0.f}, {0.f, 0.f}};

  for (int kt = 0; kt < 32; ++kt) {
    const int k0 = kt * 64;
    // ---- issue ALL global loads for this key tile up front ----
    f16x8 kf[4][2][2];  // [mt][stream][ks]
    f16x8 vf[2][4];     // [ks2][mt]
#pragma unroll
    for (int mt = 0; mt < 4; ++mt) {
      size_t ka0 = (size_t)(k0 + mt * 16 + lqi) * HD + quad * 8;
      kf[mt][0][0] = *(const f16x8*)(k_h + c1 + ka0);
      kf[mt][0][1] = *(const f16x8*)(k_h + c1 + ka0 + 32);
      kf[mt][1][0] = *(const f16x8*)(k_h + c2 + ka0);
      kf[mt][1][1] = *(const f16x8*)(k_h + c2 + ka0 + 32);
    }
#pragma unroll
    for (int ks2 = 0; ks2 < 2; ++ks2)
#pragma unroll
      for (int mt = 0; mt < 4; ++mt)
        vf[ks2][mt] = *(const f16x8*)(vt_h + vtb +
                                      (size_t)(mt * 16 + lqi) * S_LEN + k0 +
                                      ks2 * 32 + quad * 8);

    // ---- scores + exp + P store ----
#pragma unroll
    for (int mt = 0; mt < 4; ++mt) {
#pragma unroll
      for (int str = 0; str < 2; ++str)
#pragma unroll
        for (int nt = 0; nt < 2; ++nt) {
          f32x4 s = (f32x4){0.f, 0.f, 0.f, 0.f};
          s = __builtin_amdgcn_mfma_f32_16x16x32_f16(kf[mt][str][0],
                                                     qf[str][nt][0], s, 0, 0, 0);
          s = __builtin_amdgcn_mfma_f32_16x16x32_f16(kf[mt][str][1],
                                                     qf[str][nt][1], s, 0, 0, 0);
          float e0 = __builtin_amdgcn_exp2f(s[0] * SCALE_LOG2E);
          float e1 = __builtin_amdgcn_exp2f(s[1] * SCALE_LOG2E);
          float e2 = __builtin_amdgcn_exp2f(s[2] * SCALE_LOG2E);
          float e3 = __builtin_amdgcn_exp2f(s[3] * SCALE_LOG2E);
          lsum[str][nt] += (e0 + e1) + (e2 + e3);
          union { f16x4 v; f16x2 h2[2]; } pu;
          pu.h2[0] = __builtin_amdgcn_cvt_pkrtz(e0, e1);
          pu.h2[1] = __builtin_amdgcn_cvt_pkrtz(e2, e3);
          *(f16x4*)&P_lds[str][nt * 16 + lqi][mt * 16 + quad * 4] = pu.v;
        }
    }
    // ---- PV (V fragments already in registers) ----
#pragma unroll
    for (int ks2 = 0; ks2 < 2; ++ks2) {
      f16x8 pf[2][2];
#pragma unroll
      for (int str = 0; str < 2; ++str)
#pragma unroll
        for (int nt = 0; nt < 2; ++nt)
          pf[str][nt] =
              *(const f16x8*)&P_lds[str][nt * 16 + lqi][ks2 * 32 + quad * 8];
#pragma unroll
      for (int mt = 0; mt < 4; ++mt) {
#pragma unroll
        for (int str = 0; str < 2; ++str)
#pragma unroll
          for (int nt = 0; nt < 2; ++nt)
            O[str][mt][nt] = __builtin_amdgcn_mfma_f32_16x16x32_f16(
                vf[ks2][mt], pf[str][nt], O[str][mt][nt], 0, 0, 0);
      }
    }
  }

  const float lam0 = lam_init_p[0];
  const float lam = expf(lq1[h] * lk1[h]) - expf(lq2[h] * lk2[h]) + lam0;
#pragma unroll
  for (int str = 0; str < 2; ++str)
#pragma unroll
    for (int nt = 0; nt < 2; ++nt) {
      float v = lsum[str][nt];
      v += __shfl_xor(v, 16);
      v += __shfl_xor(v, 32);
      lsum[str][nt] = v;
    }
#pragma unroll
  for (int nt = 0; nt < 2; ++nt) {
    float il1 = 1.f / lsum[0][nt];
    float il2 = lam / lsum[1][nt];
    int q = q0 + nt * 16 + lqi;
#pragma unroll
    for (int mt = 0; mt < 4; ++mt) {
      f32x4 o;
#pragma unroll
      for (int i = 0; i < 4; ++i)
        o[i] = O[0][mt][nt][i] * il1 - O[1][mt][nt][i] * il2;
      *(f32x4*)(out + ((size_t)(b * S_LEN + q)) * THD_ + h * HD + mt * 16 +
                quad * 4) = o;
    }
  }
}

// ---------------------------------------------------------------------------
// GroupNorm over 64-elem head groups, d_out fp32 -> gn_h fp16,
// fused * (1 - lambda_init).
// ---------------------------------------------------------------------------
__global__ __launch_bounds__(256) void gn_kernel(
    const float* __restrict__ src, __half* __restrict__ dst,
    const float* __restrict__ gw, const float* __restrict__ gb,
    const float* __restrict__ lam_init_p) {
  int g = blockIdx.x * 4 + (threadIdx.x >> 6);
  int lane = threadIdx.x & 63;
  float v = src[(size_t)g * 64 + lane];
  float s = v, sq = v * v;
#pragma unroll
  for (int off = 32; off; off >>= 1) {
    s += __shfl_xor(s, off);
    sq += __shfl_xor(sq, off);
  }
  float mean = s * (1.f / 64.f);
  float var = sq * (1.f / 64.f) - mean * mean;
  float rs = rsqrtf(var + 1e-5f);
  int h = g & 15;
  float w = gw[h * 64 + lane], bb = gb[h * 64 + lane];
  dst[(size_t)g * 64 + lane] =
      __float2half(((v - mean) * rs * w + bb) * (1.f - lam_init_p[0]));
}

// ---------------------------------------------------------------------------
extern "C" void kernel_launch(void* const* d_in, const int* in_sizes, int n_in,
                              void* d_out, int out_size, void* d_ws,
                              size_t ws_size, hipStream_t stream) {
  const float* x = (const float*)d_in[0];
  const float* Wq = (const float*)d_in[1];
  const float* Wk = (const float*)d_in[2];
  const float* Wv = (const float*)d_in[3];
  const float* Wo = (const float*)d_in[4];
  const float* lq1 = (const float*)d_in[5];
  const float* lk1 = (const float*)d_in[6];
  const float* lq2 = (const float*)d_in[7];
  const float* lk2 = (const float*)d_in[8];
  const float* lam_init = (const float*)d_in[9];
  const float* gnw = (const float*)d_in[10];
  const float* gnb = (const float*)d_in[11];
  float* out = (float*)d_out;

  __half* q_h = (__half*)d_ws;         // region A
  __half* k_h = q_h + 8388608;         // region B
  __half* vt_h = k_h + 8388608;        // region C
  __half* WqT = vt_h;                  // C[0 : 2097152)   (dead after k-GEMM)
  __half* WkT = vt_h + 2097152;        // C[2097152 : 4194304)
  __half* WoT = q_h;                   // A[0 : 1048576)   (q dead after attn)
  __half* gn_h = q_h + 1048576;        // A[1048576 : 5242880)

  dim3 blk(256);
  // weight transposes (fp32 -> fp16 [n][k])
  wt_kernel<<<1024, blk, 0, stream>>>(Wq, WqT, 2047, 11);
  wt_kernel<<<1024, blk, 0, stream>>>(Wk, WkT, 2047, 11);
  // projections (MFMA, fused RoPE for q/k); 128m x 64n tiles
  mfma_gemm<0><<<dim3(32, 32), blk, 0, stream>>>(x, WqT, q_h);
  mfma_gemm<0><<<dim3(32, 32), blk, 0, stream>>>(x, WkT, k_h);
  mfma_gemm<2><<<dim3(16, 32), blk, 0, stream>>>(x, Wv, vt_h);
  // differential attention -> d_out (1-wave blocks, hoisted loads)
  attn_kernel<<<dim3(64, 32), dim3(64), 0, stream>>>(
      q_h, k_h, vt_h, out, lq1, lk1, lq2, lk2, lam_init);
  // Wo transpose into dead q region, then GroupNorm, then output projection
  wt_kernel<<<512, blk, 0, stream>>>(Wo, WoT, 1023, 10);
  gn_kernel<<<16384, blk, 0, stream>>>(out, gn_h, gnw, gnb, lam_init);
  mfma_gemm<3><<<dim3(16, 32), blk, 0, stream>>>(gn_h, WoT, out);
}

// Round 7
// 338.777 us; speedup vs baseline: 5.8279x; 1.2544x over previous
//
#include <hip/hip_runtime.h>
#include <hip/hip_fp16.h>
#include <math.h>

#define NH     16
#define HD     64
#define S_LEN  2048
#define THD_   1024
// exp(s*0.125) = exp2(s * 0.125 * log2(e))
#define SCALE_LOG2E 0.18033688011112042f

typedef __fp16 f16x8 __attribute__((ext_vector_type(8)));
typedef __fp16 f16x4 __attribute__((ext_vector_type(4)));
typedef __fp16 f16x2 __attribute__((ext_vector_type(2)));
typedef float  f32x4 __attribute__((ext_vector_type(4)));

// ws layout (half-elements; total 41,943,040 B, proven safe):
//   region A @ 0        : q_h  8,388,608   [b][comp][h][s][hd]
//   region B @ 8388608  : k_h  8,388,608   same layout
//   region C @ 16777216 : vt_h 4,194,304   [b][h][hd][s]
// time-shared:
//   WqT fp16 @ B[0:2097152)        (dead once q-GEMM done; k-GEMM overwrites)
//   WkT fp16 @ C[0:2097152)        (dead once k-GEMM done; v-GEMM overwrites)
//   rope tab fp32[2048][32][2] @ C[2097152:2359296) (dead before v-GEMM)
//   WoT @ A[0:1048576), gn_h @ A[1048576:5242880)   (A dead after attn)

// ---------------------------------------------------------------------------
// Weight transpose+cast: W[k][n] fp32 (row-major, K=1024) -> WT[n][k] fp16.
// ---------------------------------------------------------------------------
__global__ __launch_bounds__(256) void wt_kernel(const float* __restrict__ W,
                                                 __half* __restrict__ WT,
                                                 int nmask, int nshift) {
  int id = blockIdx.x * 256 + threadIdx.x;
  int n = id & nmask;
  int k8 = (id >> nshift) * 8;
  int N = nmask + 1;
  f16x8 h;
#pragma unroll
  for (int j = 0; j < 8; ++j)
    h[j] = (__fp16)W[(size_t)(k8 + j) * N + n];
  *(f16x8*)(WT + (size_t)n * 1024 + k8) = h;
}

// ---------------------------------------------------------------------------
// RoPE cos/sin table: tab[s][p] = {cos,sin}(s * 10000^(-p/32)), 2048x32.
// ---------------------------------------------------------------------------
__global__ __launch_bounds__(256) void rope_tab_kernel(float2* __restrict__ tab) {
  int id = blockIdx.x * 256 + threadIdx.x;  // 65536
  int p = id & 31;
  int s = id >> 5;
  float inv = expf(-0.28782313662425574f * (float)p);
  float sn, cs;
  sincosf((float)s * inv, &sn, &cs);
  tab[id] = make_float2(cs, sn);
}

// ---------------------------------------------------------------------------
// fp16 MFMA GEMM: C = A(4096 x 1024) * B(1024 x N). 128m x 64n tile, BK=64.
// 4 waves; wave w computes rows [w*32, w*32+32) x all 64 cols.
// MODE 0: A = x fp32 (cast in staging), B = WT fp16; fused-RoPE epilogue
//         (table lookup), scatter fp16 to [b][comp][h][s][hd]
// MODE 2: A = x fp32, B = raw Wv fp32 via coalesced column gather;
//         epilogue scatter fp16 to vt [b][h][hd][s]
// MODE 3: A = gn_h fp16, B = WoT fp16; epilogue fp32 row-major to d_out
// ---------------------------------------------------------------------------
template <int MODE>
__global__ __launch_bounds__(256) void mfma_gemm(const void* __restrict__ Ap,
                                                 const void* __restrict__ Bp,
                                                 void* __restrict__ Cp,
                                                 const float2* __restrict__ tab) {
  __shared__ __fp16 As[128][72];
  __shared__ __fp16 Bs[64][72];
  const int t = threadIdx.x;
  const int w = t >> 6, lane = t & 63;
  const int quad = lane >> 4, lqi = lane & 15;
  const int wm = w * 32;
  const int n0 = blockIdx.x * 64, m0 = blockIdx.y * 128;

  f32x4 acc[2][4];
#pragma unroll
  for (int mt = 0; mt < 2; ++mt)
#pragma unroll
    for (int nt = 0; nt < 4; ++nt) acc[mt][nt] = (f32x4){0.f, 0.f, 0.f, 0.f};

  const int srow = t >> 3;         // staging row base (0..31)
  const int sc8 = (t & 7) * 8;     // staging col (halves)
  const int gn_ = t & 63;          // gather: n within tile
  const int gk0 = (t >> 6) * 8;    // gather: k base (0,8,16,24)

  for (int k0 = 0; k0 < 1024; k0 += 64) {
    if (k0) __syncthreads();
    // ---- A staging ----
    if (MODE == 3) {
      const __half* A16 = (const __half*)Ap;
#pragma unroll
      for (int p = 0; p < 4; ++p) {
        int row = srow + 32 * p;
        *(f16x8*)&As[row][sc8] =
            *(const f16x8*)(A16 + (size_t)(m0 + row) * 1024 + k0 + sc8);
      }
    } else {
      const float* A32 = (const float*)Ap;
#pragma unroll
      for (int p = 0; p < 4; ++p) {
        int row = srow + 32 * p;
        const float* src = A32 + (size_t)(m0 + row) * 1024 + k0 + sc8;
        float4 u = *(const float4*)src;
        float4 v = *(const float4*)(src + 4);
        f16x8 h;
        h[0] = (__fp16)u.x; h[1] = (__fp16)u.y;
        h[2] = (__fp16)u.z; h[3] = (__fp16)u.w;
        h[4] = (__fp16)v.x; h[5] = (__fp16)v.y;
        h[6] = (__fp16)v.z; h[7] = (__fp16)v.w;
        *(f16x8*)&As[row][sc8] = h;
      }
    }
    // ---- B staging ----
    if (MODE == 2) {
      const float* B32 = (const float*)Bp;  // Wv row-major [k][1024]
#pragma unroll
      for (int p = 0; p < 2; ++p) {
        int kc = gk0 + 32 * p;
        f16x8 h;
#pragma unroll
        for (int j = 0; j < 8; ++j)
          h[j] = (__fp16)B32[(size_t)(k0 + kc + j) * 1024 + n0 + gn_];
        *(f16x8*)&Bs[gn_][kc] = h;
      }
    } else {
      const __half* B16 = (const __half*)Bp;  // WT [n][k]
      if (srow < 32) {
#pragma unroll
        for (int p = 0; p < 2; ++p) {
          int row = srow + 32 * p;
          *(f16x8*)&Bs[row][sc8] =
              *(const f16x8*)(B16 + (size_t)(n0 + row) * 1024 + k0 + sc8);
        }
      }
    }
    __syncthreads();
    // ---- MFMA ----
#pragma unroll
    for (int ks = 0; ks < 2; ++ks) {
      f16x8 af[2], bf[4];
#pragma unroll
      for (int mt = 0; mt < 2; ++mt)
        af[mt] = *(const f16x8*)&As[wm + mt * 16 + lqi][ks * 32 + quad * 8];
#pragma unroll
      for (int nt = 0; nt < 4; ++nt)
        bf[nt] = *(const f16x8*)&Bs[nt * 16 + lqi][ks * 32 + quad * 8];
#pragma unroll
      for (int mt = 0; mt < 2; ++mt)
#pragma unroll
        for (int nt = 0; nt < 4; ++nt)
          acc[mt][nt] = __builtin_amdgcn_mfma_f32_16x16x32_f16(
              af[mt], bf[nt], acc[mt][nt], 0, 0, 0);
    }
  }

  // ---- epilogue ----
  const int b = m0 >> 11;
  const int s0 = (m0 & 2047) + wm + quad * 4;
  if (MODE == 0) {
    __half* dst = (__half*)Cp;
    const int comp = n0 >> 10, hh = (n0 >> 6) & 15;
    __half* base = dst + ((size_t)(b * 2 + comp) * NH + hh) * (size_t)S_LEN * HD;
#pragma unroll
    for (int nt = 0; nt < 2; ++nt) {
      int p = nt * 16 + lqi;
#pragma unroll
      for (int mt = 0; mt < 2; ++mt) {
#pragma unroll
        for (int i = 0; i < 4; ++i) {
          int s = s0 + mt * 16 + i;
          float2 cs = tab[s * 32 + p];
          float x1 = acc[mt][nt][i], x2 = acc[mt][nt + 2][i];
          base[(size_t)s * HD + p] = __float2half(x1 * cs.x - x2 * cs.y);
          base[(size_t)s * HD + p + 32] = __float2half(x2 * cs.x + x1 * cs.y);
        }
      }
    }
  } else if (MODE == 2) {
    __half* vt = (__half*)Cp;
    const int hh = n0 >> 6;
#pragma unroll
    for (int nt = 0; nt < 4; ++nt) {
      int hd = nt * 16 + lqi;
      __half* base = vt + (((size_t)b * NH + hh) * HD + hd) * S_LEN;
#pragma unroll
      for (int mt = 0; mt < 2; ++mt) {
        f16x4 hv;
#pragma unroll
        for (int i = 0; i < 4; ++i) hv[i] = (__fp16)acc[mt][nt][i];
        *(f16x4*)(base + s0 + mt * 16) = hv;
      }
    }
  } else {
    float* Co = (float*)Cp;
#pragma unroll
    for (int mt = 0; mt < 2; ++mt)
#pragma unroll
      for (int i = 0; i < 4; ++i) {
        int m = m0 + wm + mt * 16 + quad * 4 + i;
#pragma unroll
        for (int nt = 0; nt < 4; ++nt)
          Co[(size_t)m * 1024 + n0 + nt * 16 + lqi] = acc[mt][nt][i];
      }
  }
}

// ---------------------------------------------------------------------------
// Differential attention, MFMA (16x16x32 f16), 4-wave blocks with LDS-shared
// K/V tiles. R6 restructure: R5 counters (MFMA 14.5%, VALU 20.5%, HBM 8%,
// occupancy 22%) showed per-wave private K/V loads (24/kt, 1.6 GB aggregate)
// left the kernel latency-bound. Now each 256t block stages the 64-key tile
// ONCE in fragment-ordered LDS chunks (1 KB each; ds ops are b128 at
// base+lane*16, conflict-free), shared by all 4 waves -> 6 global loads per
// wave-kt, deterministic LDS-fed fragments, 2 barriers/kt, 2 blocks/CU.
// ---------------------------------------------------------------------------
__global__ __launch_bounds__(256, 2) void attn_kernel(
    const __half* __restrict__ q_h, const __half* __restrict__ k_h,
    const __half* __restrict__ vt_h, float* __restrict__ out,
    const float* __restrict__ lq1, const float* __restrict__ lk1,
    const float* __restrict__ lq2, const float* __restrict__ lk2,
    const float* __restrict__ lam_init_p) {
  // K chunks 0..15: [str][mt][ks]; V chunks 16..23: [ks2][mt]. 1 KB each.
  __shared__ __half KV[24][512];
  __shared__ __half P_lds[4][2][32][72];  // wave-private P

  const int t = threadIdx.x;
  const int w = t >> 6, lane = t & 63;
  const int quad = lane >> 4, lqi = lane & 15;
  const int qt = blockIdx.x;   // 0..15 (128-query tiles)
  const int bh = blockIdx.y;   // 0..31
  const int b = bh >> 4, h = bh & 15;

  const size_t c1 = ((size_t)(b * 2 + 0) * NH + h) * (size_t)S_LEN * HD;
  const size_t c2 = ((size_t)(b * 2 + 1) * NH + h) * (size_t)S_LEN * HD;
  const size_t vtb = ((size_t)b * NH + h) * (size_t)HD * S_LEN;
  const int q0 = qt * 128 + w * 32;

  f16x8 qf[2][2][2];  // [stream][nt][ks]
#pragma unroll
  for (int nt = 0; nt < 2; ++nt)
#pragma unroll
    for (int ks = 0; ks < 2; ++ks) {
      size_t a = (size_t)(q0 + nt * 16 + lqi) * HD + ks * 32 + quad * 8;
      qf[0][nt][ks] = *(const f16x8*)(q_h + c1 + a);
      qf[1][nt][ks] = *(const f16x8*)(q_h + c2 + a);
    }

  f32x4 O[2][4][2];
#pragma unroll
  for (int s = 0; s < 2; ++s)
#pragma unroll
    for (int mt = 0; mt < 4; ++mt)
#pragma unroll
      for (int nt = 0; nt < 2; ++nt) O[s][mt][nt] = (f32x4){0.f, 0.f, 0.f, 0.f};
  float lsum[2][2] = {{0.f, 0.f}, {0.f, 0.f}};

  for (int kt = 0; kt < 32; ++kt) {
    const int k0 = kt * 64;
    __syncthreads();  // all waves done reading previous KV tile
    // ---- cooperative staging: wave w stages chunks w, w+4, ..., w+20 ----
#pragma unroll
    for (int ci = 0; ci < 6; ++ci) {
      const int c = w + ci * 4;
      const __half* g;
      if (c < 16) {
        int str = c >> 3, mt = (c >> 1) & 3, ks = c & 1;
        g = k_h + (str ? c2 : c1) +
            (size_t)(k0 + mt * 16 + lqi) * HD + ks * 32 + quad * 8;
      } else {
        int cc = c - 16;
        int ks2 = cc >> 2, mt = cc & 3;
        g = vt_h + vtb + (size_t)(mt * 16 + lqi) * S_LEN + k0 + ks2 * 32 +
            quad * 8;
      }
      *(f16x8*)&KV[c][lane * 8] = *(const f16x8*)g;
    }
    __syncthreads();  // tile visible to all waves

    // ---- scores + exp + P store ----
#pragma unroll
    for (int mt = 0; mt < 4; ++mt) {
#pragma unroll
      for (int str = 0; str < 2; ++str) {
        f16x8 kf0 = *(const f16x8*)&KV[str * 8 + mt * 2 + 0][lane * 8];
        f16x8 kf1 = *(const f16x8*)&KV[str * 8 + mt * 2 + 1][lane * 8];
#pragma unroll
        for (int nt = 0; nt < 2; ++nt) {
          f32x4 s = (f32x4){0.f, 0.f, 0.f, 0.f};
          s = __builtin_amdgcn_mfma_f32_16x16x32_f16(kf0, qf[str][nt][0], s,
                                                     0, 0, 0);
          s = __builtin_amdgcn_mfma_f32_16x16x32_f16(kf1, qf[str][nt][1], s,
                                                     0, 0, 0);
          float e0 = __builtin_amdgcn_exp2f(s[0] * SCALE_LOG2E);
          float e1 = __builtin_amdgcn_exp2f(s[1] * SCALE_LOG2E);
          float e2 = __builtin_amdgcn_exp2f(s[2] * SCALE_LOG2E);
          float e3 = __builtin_amdgcn_exp2f(s[3] * SCALE_LOG2E);
          lsum[str][nt] += (e0 + e1) + (e2 + e3);
          union { f16x4 v; f16x2 h2[2]; } pu;
          pu.h2[0] = __builtin_amdgcn_cvt_pkrtz(e0, e1);
          pu.h2[1] = __builtin_amdgcn_cvt_pkrtz(e2, e3);
          *(f16x4*)&P_lds[w][str][nt * 16 + lqi][mt * 16 + quad * 4] = pu.v;
        }
      }
    }
    // ---- PV ----
#pragma unroll
    for (int ks2 = 0; ks2 < 2; ++ks2) {
      f16x8 pf[2][2];
#pragma unroll
      for (int str = 0; str < 2; ++str)
#pragma unroll
        for (int nt = 0; nt < 2; ++nt)
          pf[str][nt] = *(const f16x8*)&P_lds[w][str][nt * 16 + lqi]
                                             [ks2 * 32 + quad * 8];
#pragma unroll
      for (int mt = 0; mt < 4; ++mt) {
        f16x8 vf = *(const f16x8*)&KV[16 + ks2 * 4 + mt][lane * 8];
#pragma unroll
        for (int str = 0; str < 2; ++str)
#pragma unroll
          for (int nt = 0; nt < 2; ++nt)
            O[str][mt][nt] = __builtin_amdgcn_mfma_f32_16x16x32_f16(
                vf, pf[str][nt], O[str][mt][nt], 0, 0, 0);
      }
    }
  }

  const float lam0 = lam_init_p[0];
  const float lam = expf(lq1[h] * lk1[h]) - expf(lq2[h] * lk2[h]) + lam0;
#pragma unroll
  for (int str = 0; str < 2; ++str)
#pragma unroll
    for (int nt = 0; nt < 2; ++nt) {
      float v = lsum[str][nt];
      v += __shfl_xor(v, 16);
      v += __shfl_xor(v, 32);
      lsum[str][nt] = v;
    }
#pragma unroll
  for (int nt = 0; nt < 2; ++nt) {
    float il1 = 1.f / lsum[0][nt];
    float il2 = lam / lsum[1][nt];
    int q = q0 + nt * 16 + lqi;
#pragma unroll
    for (int mt = 0; mt < 4; ++mt) {
      f32x4 o;
#pragma unroll
      for (int i = 0; i < 4; ++i)
        o[i] = O[0][mt][nt][i] * il1 - O[1][mt][nt][i] * il2;
      *(f32x4*)(out + ((size_t)(b * S_LEN + q)) * THD_ + h * HD + mt * 16 +
                quad * 4) = o;
    }
  }
}

// ---------------------------------------------------------------------------
// GroupNorm over 64-elem head groups, d_out fp32 -> gn_h fp16,
// fused * (1 - lambda_init).
// ---------------------------------------------------------------------------
__global__ __launch_bounds__(256) void gn_kernel(
    const float* __restrict__ src, __half* __restrict__ dst,
    const float* __restrict__ gw, const float* __restrict__ gb,
    const float* __restrict__ lam_init_p) {
  int g = blockIdx.x * 4 + (threadIdx.x >> 6);
  int lane = threadIdx.x & 63;
  float v = src[(size_t)g * 64 + lane];
  float s = v, sq = v * v;
#pragma unroll
  for (int off = 32; off; off >>= 1) {
    s += __shfl_xor(s, off);
    sq += __shfl_xor(sq, off);
  }
  float mean = s * (1.f / 64.f);
  float var = sq * (1.f / 64.f) - mean * mean;
  float rs = rsqrtf(var + 1e-5f);
  int h = g & 15;
  float w = gw[h * 64 + lane], bb = gb[h * 64 + lane];
  dst[(size_t)g * 64 + lane] =
      __float2half(((v - mean) * rs * w + bb) * (1.f - lam_init_p[0]));
}

// ---------------------------------------------------------------------------
extern "C" void kernel_launch(void* const* d_in, const int* in_sizes, int n_in,
                              void* d_out, int out_size, void* d_ws,
                              size_t ws_size, hipStream_t stream) {
  const float* x = (const float*)d_in[0];
  const float* Wq = (const float*)d_in[1];
  const float* Wk = (const float*)d_in[2];
  const float* Wv = (const float*)d_in[3];
  const float* Wo = (const float*)d_in[4];
  const float* lq1 = (const float*)d_in[5];
  const float* lk1 = (const float*)d_in[6];
  const float* lq2 = (const float*)d_in[7];
  const float* lk2 = (const float*)d_in[8];
  const float* lam_init = (const float*)d_in[9];
  const float* gnw = (const float*)d_in[10];
  const float* gnb = (const float*)d_in[11];
  float* out = (float*)d_out;

  __half* q_h = (__half*)d_ws;          // region A
  __half* k_h = q_h + 8388608;          // region B
  __half* vt_h = k_h + 8388608;         // region C
  __half* WqT = k_h;                    // B[0:2097152)  (q-GEMM reads, then k-GEMM overwrites)
  __half* WkT = vt_h;                   // C[0:2097152)  (k-GEMM reads, then v-GEMM overwrites)
  float2* tab = (float2*)(vt_h + 2097152);  // C[2097152:2359296) as fp32 pairs
  __half* WoT = q_h;                    // A[0:1048576)  (q dead after attn)
  __half* gn_h = q_h + 1048576;         // A[1048576:5242880)

  dim3 blk(256);
  // weight transposes (fp32 -> fp16 [n][k]) + rope table
  wt_kernel<<<1024, blk, 0, stream>>>(Wq, WqT, 2047, 11);
  wt_kernel<<<1024, blk, 0, stream>>>(Wk, WkT, 2047, 11);
  rope_tab_kernel<<<256, blk, 0, stream>>>(tab);
  // projections (MFMA, fused table-RoPE for q/k); 128m x 64n tiles
  mfma_gemm<0><<<dim3(32, 32), blk, 0, stream>>>(x, WqT, q_h, tab);
  mfma_gemm<0><<<dim3(32, 32), blk, 0, stream>>>(x, WkT, k_h, tab);
  mfma_gemm<2><<<dim3(16, 32), blk, 0, stream>>>(x, Wv, vt_h, nullptr);
  // differential attention -> d_out (4-wave blocks, LDS-shared K/V)
  attn_kernel<<<dim3(16, 32), blk, 0, stream>>>(q_h, k_h, vt_h, out, lq1, lk1,
                                                lq2, lk2, lam_init);
  // Wo transpose into dead q region, then GroupNorm, then output projection
  wt_kernel<<<512, blk, 0, stream>>>(Wo, WoT, 1023, 10);
  gn_kernel<<<16384, blk, 0, stream>>>(out, gn_h, gnw, gnb, lam_init);
  mfma_gemm<3><<<dim3(16, 32), blk, 0, stream>>>(gn_h, WoT, out, nullptr);
}

// Round 8
// 331.358 us; speedup vs baseline: 5.9584x; 1.0224x over previous
//
#include <hip/hip_runtime.h>
#include <hip/hip_fp16.h>
#include <math.h>

#define NH     16
#define HD     64
#define S_LEN  2048
#define THD_   1024
// exp(s*0.125) = exp2(s * 0.125 * log2(e))
#define SCALE_LOG2E 0.18033688011112042f

typedef __fp16 f16x8 __attribute__((ext_vector_type(8)));
typedef __fp16 f16x4 __attribute__((ext_vector_type(4)));
typedef __fp16 f16x2 __attribute__((ext_vector_type(2)));
typedef float  f32x4 __attribute__((ext_vector_type(4)));

// ws layout (half-elements; total 41,943,040 B, proven safe):
//   region A @ 0        : q_h  8,388,608   [b][comp][h][s][hd]
//   region B @ 8388608  : k_h  8,388,608   same layout
//   region C @ 16777216 : vt_h 4,194,304   [b][h][hd][s]
// time-shared:
//   WqT fp16 @ B[0:2097152)        (dead once q-GEMM done; k-GEMM overwrites)
//   WkT fp16 @ C[0:2097152)        (dead once k-GEMM done; v-GEMM overwrites)
//   rope tab fp32[2048][32][2] @ C[2097152:2359296) (dead before v-GEMM)
//   WoT @ A[0:1048576), gn_h @ A[1048576:5242880)   (A dead after attn)

// ---------------------------------------------------------------------------
// Shared weight-transpose body: W[k][n] fp32 -> WT[n][k] fp16.
// ---------------------------------------------------------------------------
__device__ inline void wt_body(const float* __restrict__ W,
                               __half* __restrict__ WT, int id, int nmask,
                               int nshift) {
  int n = id & nmask;
  int k8 = (id >> nshift) * 8;
  int N = nmask + 1;
  f16x8 h;
#pragma unroll
  for (int j = 0; j < 8; ++j)
    h[j] = (__fp16)W[(size_t)(k8 + j) * N + n];
  *(f16x8*)(WT + (size_t)n * 1024 + k8) = h;
}

// ---------------------------------------------------------------------------
// Fused prep: blocks [0,1024) transpose Wq; [1024,2048) transpose Wk;
// [2048,2304) fill the RoPE cos/sin table tab[s][p] (2048 x 32).
// ---------------------------------------------------------------------------
__global__ __launch_bounds__(256) void prep_kernel(
    const float* __restrict__ Wq, const float* __restrict__ Wk,
    __half* __restrict__ WqT, __half* __restrict__ WkT,
    float2* __restrict__ tab) {
  int bid = blockIdx.x;
  int t = threadIdx.x;
  if (bid < 1024) {
    wt_body(Wq, WqT, bid * 256 + t, 2047, 11);
  } else if (bid < 2048) {
    wt_body(Wk, WkT, (bid - 1024) * 256 + t, 2047, 11);
  } else {
    int id = (bid - 2048) * 256 + t;  // 65536
    int p = id & 31;
    int s = id >> 5;
    float inv = expf(-0.28782313662425574f * (float)p);
    float sn, cs;
    sincosf((float)s * inv, &sn, &cs);
    tab[id] = make_float2(cs, sn);
  }
}

// ---------------------------------------------------------------------------
// fp16 MFMA GEMM: C = A(4096 x 1024) * B(1024 x N). 128m x 64n tile, BK=64.
// 4 waves; wave w computes rows [w*32, w*32+32) x all 64 cols.
// MODE 0: A = x fp32 (cast in staging), B = WT fp16; fused-RoPE epilogue
//         (table lookup), scatter fp16 to [b][comp][h][s][hd]
// MODE 2: A = x fp32, B = raw Wv fp32 via coalesced column gather;
//         epilogue scatter fp16 to vt [b][h][hd][s]
// MODE 3: A = gn_h fp16, B = WoT fp16; epilogue fp32 row-major to d_out
// ---------------------------------------------------------------------------
template <int MODE>
__global__ __launch_bounds__(256) void mfma_gemm(const void* __restrict__ Ap,
                                                 const void* __restrict__ Bp,
                                                 void* __restrict__ Cp,
                                                 const float2* __restrict__ tab) {
  __shared__ __fp16 As[128][72];
  __shared__ __fp16 Bs[64][72];
  const int t = threadIdx.x;
  const int w = t >> 6, lane = t & 63;
  const int quad = lane >> 4, lqi = lane & 15;
  const int wm = w * 32;
  const int n0 = blockIdx.x * 64, m0 = blockIdx.y * 128;

  f32x4 acc[2][4];
#pragma unroll
  for (int mt = 0; mt < 2; ++mt)
#pragma unroll
    for (int nt = 0; nt < 4; ++nt) acc[mt][nt] = (f32x4){0.f, 0.f, 0.f, 0.f};

  const int srow = t >> 3;         // staging row base (0..31)
  const int sc8 = (t & 7) * 8;     // staging col (halves)
  const int gn_ = t & 63;          // gather: n within tile
  const int gk0 = (t >> 6) * 8;    // gather: k base (0,8,16,24)

  for (int k0 = 0; k0 < 1024; k0 += 64) {
    if (k0) __syncthreads();
    // ---- A staging ----
    if (MODE == 3) {
      const __half* A16 = (const __half*)Ap;
#pragma unroll
      for (int p = 0; p < 4; ++p) {
        int row = srow + 32 * p;
        *(f16x8*)&As[row][sc8] =
            *(const f16x8*)(A16 + (size_t)(m0 + row) * 1024 + k0 + sc8);
      }
    } else {
      const float* A32 = (const float*)Ap;
#pragma unroll
      for (int p = 0; p < 4; ++p) {
        int row = srow + 32 * p;
        const float* src = A32 + (size_t)(m0 + row) * 1024 + k0 + sc8;
        float4 u = *(const float4*)src;
        float4 v = *(const float4*)(src + 4);
        f16x8 h;
        h[0] = (__fp16)u.x; h[1] = (__fp16)u.y;
        h[2] = (__fp16)u.z; h[3] = (__fp16)u.w;
        h[4] = (__fp16)v.x; h[5] = (__fp16)v.y;
        h[6] = (__fp16)v.z; h[7] = (__fp16)v.w;
        *(f16x8*)&As[row][sc8] = h;
      }
    }
    // ---- B staging ----
    if (MODE == 2) {
      const float* B32 = (const float*)Bp;  // Wv row-major [k][1024]
#pragma unroll
      for (int p = 0; p < 2; ++p) {
        int kc = gk0 + 32 * p;
        f16x8 h;
#pragma unroll
        for (int j = 0; j < 8; ++j)
          h[j] = (__fp16)B32[(size_t)(k0 + kc + j) * 1024 + n0 + gn_];
        *(f16x8*)&Bs[gn_][kc] = h;
      }
    } else {
      const __half* B16 = (const __half*)Bp;  // WT [n][k]
      if (srow < 32) {
#pragma unroll
        for (int p = 0; p < 2; ++p) {
          int row = srow + 32 * p;
          *(f16x8*)&Bs[row][sc8] =
              *(const f16x8*)(B16 + (size_t)(n0 + row) * 1024 + k0 + sc8);
        }
      }
    }
    __syncthreads();
    // ---- MFMA ----
#pragma unroll
    for (int ks = 0; ks < 2; ++ks) {
      f16x8 af[2], bf[4];
#pragma unroll
      for (int mt = 0; mt < 2; ++mt)
        af[mt] = *(const f16x8*)&As[wm + mt * 16 + lqi][ks * 32 + quad * 8];
#pragma unroll
      for (int nt = 0; nt < 4; ++nt)
        bf[nt] = *(const f16x8*)&Bs[nt * 16 + lqi][ks * 32 + quad * 8];
#pragma unroll
      for (int mt = 0; mt < 2; ++mt)
#pragma unroll
        for (int nt = 0; nt < 4; ++nt)
          acc[mt][nt] = __builtin_amdgcn_mfma_f32_16x16x32_f16(
              af[mt], bf[nt], acc[mt][nt], 0, 0, 0);
    }
  }

  // ---- epilogue ----
  const int b = m0 >> 11;
  const int s0 = (m0 & 2047) + wm + quad * 4;
  if (MODE == 0) {
    __half* dst = (__half*)Cp;
    const int comp = n0 >> 10, hh = (n0 >> 6) & 15;
    __half* base = dst + ((size_t)(b * 2 + comp) * NH + hh) * (size_t)S_LEN * HD;
#pragma unroll
    for (int nt = 0; nt < 2; ++nt) {
      int p = nt * 16 + lqi;
#pragma unroll
      for (int mt = 0; mt < 2; ++mt) {
#pragma unroll
        for (int i = 0; i < 4; ++i) {
          int s = s0 + mt * 16 + i;
          float2 cs = tab[s * 32 + p];
          float x1 = acc[mt][nt][i], x2 = acc[mt][nt + 2][i];
          base[(size_t)s * HD + p] = __float2half(x1 * cs.x - x2 * cs.y);
          base[(size_t)s * HD + p + 32] = __float2half(x2 * cs.x + x1 * cs.y);
        }
      }
    }
  } else if (MODE == 2) {
    __half* vt = (__half*)Cp;
    const int hh = n0 >> 6;
#pragma unroll
    for (int nt = 0; nt < 4; ++nt) {
      int hd = nt * 16 + lqi;
      __half* base = vt + (((size_t)b * NH + hh) * HD + hd) * S_LEN;
#pragma unroll
      for (int mt = 0; mt < 2; ++mt) {
        f16x4 hv;
#pragma unroll
        for (int i = 0; i < 4; ++i) hv[i] = (__fp16)acc[mt][nt][i];
        *(f16x4*)(base + s0 + mt * 16) = hv;
      }
    }
  } else {
    float* Co = (float*)Cp;
#pragma unroll
    for (int mt = 0; mt < 2; ++mt)
#pragma unroll
      for (int i = 0; i < 4; ++i) {
        int m = m0 + wm + mt * 16 + quad * 4 + i;
#pragma unroll
        for (int nt = 0; nt < 4; ++nt)
          Co[(size_t)m * 1024 + n0 + nt * 16 + lqi] = acc[mt][nt][i];
      }
  }
}

// ---------------------------------------------------------------------------
// Differential attention, MFMA (16x16x32 f16), 4-wave blocks, LDS-shared K/V
// tiles with REGISTER-PREFETCH pipeline. R7: R6 counters (MFMA 27%, VALU 39%,
// HBM 15%, occ 21%) showed the kt-loop still latency-bound: staging loads sat
// between the two barriers, exposing global latency every iteration. Now the
// 6 staging loads for tile kt+1 issue right after the visibility barrier and
// land in registers while tile kt's ~1100 cyc of MFMA+exp executes; the next
// iteration only ds_writes them. LDS unchanged (60 KB, 2 blocks/CU).
// ---------------------------------------------------------------------------
__global__ __launch_bounds__(256, 2) void attn_kernel(
    const __half* __restrict__ q_h, const __half* __restrict__ k_h,
    const __half* __restrict__ vt_h, float* __restrict__ out,
    const float* __restrict__ lq1, const float* __restrict__ lk1,
    const float* __restrict__ lq2, const float* __restrict__ lk2,
    const float* __restrict__ lam_init_p) {
  // K chunks 0..15: [str][mt][ks]; V chunks 16..23: [ks2][mt]. 1 KB each.
  __shared__ __half KV[24][512];
  __shared__ __half P_lds[4][2][32][72];  // wave-private P

  const int t = threadIdx.x;
  const int w = t >> 6, lane = t & 63;
  const int quad = lane >> 4, lqi = lane & 15;
  const int qt = blockIdx.x;   // 0..15 (128-query tiles)
  const int bh = blockIdx.y;   // 0..31
  const int b = bh >> 4, h = bh & 15;

  const size_t c1 = ((size_t)(b * 2 + 0) * NH + h) * (size_t)S_LEN * HD;
  const size_t c2 = ((size_t)(b * 2 + 1) * NH + h) * (size_t)S_LEN * HD;
  const size_t vtb = ((size_t)b * NH + h) * (size_t)HD * S_LEN;
  const int q0 = qt * 128 + w * 32;

  f16x8 qf[2][2][2];  // [stream][nt][ks]
#pragma unroll
  for (int nt = 0; nt < 2; ++nt)
#pragma unroll
    for (int ks = 0; ks < 2; ++ks) {
      size_t a = (size_t)(q0 + nt * 16 + lqi) * HD + ks * 32 + quad * 8;
      qf[0][nt][ks] = *(const f16x8*)(q_h + c1 + a);
      qf[1][nt][ks] = *(const f16x8*)(q_h + c2 + a);
    }

  f32x4 O[2][4][2];
#pragma unroll
  for (int s = 0; s < 2; ++s)
#pragma unroll
    for (int mt = 0; mt < 4; ++mt)
#pragma unroll
      for (int nt = 0; nt < 2; ++nt) O[s][mt][nt] = (f32x4){0.f, 0.f, 0.f, 0.f};
  float lsum[2][2] = {{0.f, 0.f}, {0.f, 0.f}};

  // staging chunk addresses: wave w owns chunks c = w + ci*4, ci in [0,6)
  auto chunk_addr = [&](int c, int k0) -> const __half* {
    if (c < 16) {
      int str = c >> 3, mt = (c >> 1) & 3, ks = c & 1;
      return k_h + (str ? c2 : c1) + (size_t)(k0 + mt * 16 + lqi) * HD +
             ks * 32 + quad * 8;
    }
    int cc = c - 16, ks2 = cc >> 2, mt = cc & 3;
    return vt_h + vtb + (size_t)(mt * 16 + lqi) * S_LEN + k0 + ks2 * 32 +
           quad * 8;
  };

  f16x8 r[6];
#pragma unroll
  for (int ci = 0; ci < 6; ++ci)
    r[ci] = *(const f16x8*)chunk_addr(w + ci * 4, 0);

  for (int kt = 0; kt < 32; ++kt) {
    if (kt) __syncthreads();  // all waves done reading previous KV tile
#pragma unroll
    for (int ci = 0; ci < 6; ++ci)
      *(f16x8*)&KV[w + ci * 4][lane * 8] = r[ci];
    __syncthreads();          // tile visible to all waves

    if (kt < 31) {  // prefetch next tile into registers during compute
#pragma unroll
      for (int ci = 0; ci < 6; ++ci)
        r[ci] = *(const f16x8*)chunk_addr(w + ci * 4, (kt + 1) * 64);
    }

    // ---- scores + exp + P store ----
#pragma unroll
    for (int mt = 0; mt < 4; ++mt) {
#pragma unroll
      for (int str = 0; str < 2; ++str) {
        f16x8 kf0 = *(const f16x8*)&KV[str * 8 + mt * 2 + 0][lane * 8];
        f16x8 kf1 = *(const f16x8*)&KV[str * 8 + mt * 2 + 1][lane * 8];
#pragma unroll
        for (int nt = 0; nt < 2; ++nt) {
          f32x4 s = (f32x4){0.f, 0.f, 0.f, 0.f};
          s = __builtin_amdgcn_mfma_f32_16x16x32_f16(kf0, qf[str][nt][0], s,
                                                     0, 0, 0);
          s = __builtin_amdgcn_mfma_f32_16x16x32_f16(kf1, qf[str][nt][1], s,
                                                     0, 0, 0);
          float e0 = __builtin_amdgcn_exp2f(s[0] * SCALE_LOG2E);
          float e1 = __builtin_amdgcn_exp2f(s[1] * SCALE_LOG2E);
          float e2 = __builtin_amdgcn_exp2f(s[2] * SCALE_LOG2E);
          float e3 = __builtin_amdgcn_exp2f(s[3] * SCALE_LOG2E);
          lsum[str][nt] += (e0 + e1) + (e2 + e3);
          union { f16x4 v; f16x2 h2[2]; } pu;
          pu.h2[0] = __builtin_amdgcn_cvt_pkrtz(e0, e1);
          pu.h2[1] = __builtin_amdgcn_cvt_pkrtz(e2, e3);
          *(f16x4*)&P_lds[w][str][nt * 16 + lqi][mt * 16 + quad * 4] = pu.v;
        }
      }
    }
    // ---- PV ----
#pragma unroll
    for (int ks2 = 0; ks2 < 2; ++ks2) {
      f16x8 pf[2][2];
#pragma unroll
      for (int str = 0; str < 2; ++str)
#pragma unroll
        for (int nt = 0; nt < 2; ++nt)
          pf[str][nt] = *(const f16x8*)&P_lds[w][str][nt * 16 + lqi]
                                             [ks2 * 32 + quad * 8];
#pragma unroll
      for (int mt = 0; mt < 4; ++mt) {
        f16x8 vf = *(const f16x8*)&KV[16 + ks2 * 4 + mt][lane * 8];
#pragma unroll
        for (int str = 0; str < 2; ++str)
#pragma unroll
          for (int nt = 0; nt < 2; ++nt)
            O[str][mt][nt] = __builtin_amdgcn_mfma_f32_16x16x32_f16(
                vf, pf[str][nt], O[str][mt][nt], 0, 0, 0);
      }
    }
  }

  const float lam0 = lam_init_p[0];
  const float lam = expf(lq1[h] * lk1[h]) - expf(lq2[h] * lk2[h]) + lam0;
#pragma unroll
  for (int str = 0; str < 2; ++str)
#pragma unroll
    for (int nt = 0; nt < 2; ++nt) {
      float v = lsum[str][nt];
      v += __shfl_xor(v, 16);
      v += __shfl_xor(v, 32);
      lsum[str][nt] = v;
    }
#pragma unroll
  for (int nt = 0; nt < 2; ++nt) {
    float il1 = 1.f / lsum[0][nt];
    float il2 = lam / lsum[1][nt];
    int q = q0 + nt * 16 + lqi;
#pragma unroll
    for (int mt = 0; mt < 4; ++mt) {
      f32x4 o;
#pragma unroll
      for (int i = 0; i < 4; ++i)
        o[i] = O[0][mt][nt][i] * il1 - O[1][mt][nt][i] * il2;
      *(f32x4*)(out + ((size_t)(b * S_LEN + q)) * THD_ + h * HD + mt * 16 +
                quad * 4) = o;
    }
  }
}

// ---------------------------------------------------------------------------
// Fused GroupNorm + Wo transpose. Blocks [0,16384): GroupNorm over 64-elem
// head groups (d_out fp32 -> gn_h fp16, * (1-lambda_init)); blocks
// [16384,16896): transpose Wo fp32 -> WoT fp16 [n][k].
// ---------------------------------------------------------------------------
__global__ __launch_bounds__(256) void gn_wt_kernel(
    const float* __restrict__ src, __half* __restrict__ dst,
    const float* __restrict__ gw, const float* __restrict__ gb,
    const float* __restrict__ lam_init_p, const float* __restrict__ Wo,
    __half* __restrict__ WoT) {
  if (blockIdx.x >= 16384) {
    wt_body(Wo, WoT, (blockIdx.x - 16384) * 256 + threadIdx.x, 1023, 10);
    return;
  }
  int g = blockIdx.x * 4 + (threadIdx.x >> 6);
  int lane = threadIdx.x & 63;
  float v = src[(size_t)g * 64 + lane];
  float s = v, sq = v * v;
#pragma unroll
  for (int off = 32; off; off >>= 1) {
    s += __shfl_xor(s, off);
    sq += __shfl_xor(sq, off);
  }
  float mean = s * (1.f / 64.f);
  float var = sq * (1.f / 64.f) - mean * mean;
  float rs = rsqrtf(var + 1e-5f);
  int h = g & 15;
  float w = gw[h * 64 + lane], bb = gb[h * 64 + lane];
  dst[(size_t)g * 64 + lane] =
      __float2half(((v - mean) * rs * w + bb) * (1.f - lam_init_p[0]));
}

// ---------------------------------------------------------------------------
extern "C" void kernel_launch(void* const* d_in, const int* in_sizes, int n_in,
                              void* d_out, int out_size, void* d_ws,
                              size_t ws_size, hipStream_t stream) {
  const float* x = (const float*)d_in[0];
  const float* Wq = (const float*)d_in[1];
  const float* Wk = (const float*)d_in[2];
  const float* Wv = (const float*)d_in[3];
  const float* Wo = (const float*)d_in[4];
  const float* lq1 = (const float*)d_in[5];
  const float* lk1 = (const float*)d_in[6];
  const float* lq2 = (const float*)d_in[7];
  const float* lk2 = (const float*)d_in[8];
  const float* lam_init = (const float*)d_in[9];
  const float* gnw = (const float*)d_in[10];
  const float* gnb = (const float*)d_in[11];
  float* out = (float*)d_out;

  __half* q_h = (__half*)d_ws;          // region A
  __half* k_h = q_h + 8388608;          // region B
  __half* vt_h = k_h + 8388608;         // region C
  __half* WqT = k_h;                    // B[0:2097152)  (dead after q-GEMM)
  __half* WkT = vt_h;                   // C[0:2097152)  (dead after k-GEMM)
  float2* tab = (float2*)(vt_h + 2097152);  // C[2097152:2359296) fp32 pairs
  __half* WoT = q_h;                    // A[0:1048576)  (q dead after attn)
  __half* gn_h = q_h + 1048576;         // A[1048576:5242880)

  dim3 blk(256);
  // fused prep: Wq/Wk transposes + rope table (1 dispatch)
  prep_kernel<<<2304, blk, 0, stream>>>(Wq, Wk, WqT, WkT, tab);
  // projections (MFMA, fused table-RoPE for q/k); 128m x 64n tiles
  mfma_gemm<0><<<dim3(32, 32), blk, 0, stream>>>(x, WqT, q_h, tab);
  mfma_gemm<0><<<dim3(32, 32), blk, 0, stream>>>(x, WkT, k_h, tab);
  mfma_gemm<2><<<dim3(16, 32), blk, 0, stream>>>(x, Wv, vt_h, nullptr);
  // differential attention -> d_out (LDS-shared K/V + register prefetch)
  attn_kernel<<<dim3(16, 32), blk, 0, stream>>>(q_h, k_h, vt_h, out, lq1, lk1,
                                                lq2, lk2, lam_init);
  // fused GroupNorm + Wo transpose (1 dispatch)
  gn_wt_kernel<<<16896, blk, 0, stream>>>(out, gn_h, gnw, gnb, lam_init, Wo,
                                          WoT);
  // output projection: gn_h @ WoT -> d_out
  mfma_gemm<3><<<dim3(16, 32), blk, 0, stream>>>(gn_h, WoT, out, nullptr);
}